// Round 2
// baseline (637.546 us; speedup 1.0000x reference)
//
#include <hip/hip_runtime.h>

// ---------------------------------------------------------------------------
// ATFA: dual-axis conv-attention, MI355X fp16-MFMA implementation.
// Round 2: conv_qkv rewritten as 3-buffer LDS pipeline (counted vmcnt(3),
// ONE barrier per K-tile, never drains to 0 in main loop), 2 blocks/CU,
// XCD-swizzled grid. Everything else unchanged from the passing round-1.
// ---------------------------------------------------------------------------

typedef _Float16 f16;
typedef _Float16 f16x8 __attribute__((ext_vector_type(8)));
typedef float    f32x4 __attribute__((ext_vector_type(4)));

#define B_   2
#define T_   249
#define F_   64
#define TP   251     // T + 2 (padded)
#define FP   66      // F + 2 (padded)
#define PIXB (T_*F_) // 15936 pixels per batch
#define NPIX (B_*PIXB)
#define LPAD 256     // padded attention length for the T-axis heads

static constexpr size_t FUSED_BYTES = (size_t)B_*TP*FP*768*2;  // 50,890,752
static constexpr size_t XPAD_BYTES  = (size_t)B_*TP*FP*256*2;  // 16,963,584
static constexpr size_t QF_BYTES    = (size_t)B_*64*LPAD*256*2;// 16,777,216
static constexpr size_t QT_BYTES    = (size_t)B_*T_*64*256*2;  // 16,318,464
static constexpr size_t WT_BYTES    = (size_t)9*1536*256*2;    //  7,077,888
static constexpr size_t WFT_BYTES   = (size_t)9*64*768*2;      //    884,736

static constexpr size_t OFF_FUSED = 0;
static constexpr size_t OFF_XPAD  = OFF_FUSED + FUSED_BYTES;
static constexpr size_t OFF_QF    = OFF_XPAD  + XPAD_BYTES;
static constexpr size_t OFF_KF    = OFF_QF + QF_BYTES;
static constexpr size_t OFF_VF    = OFF_KF + QF_BYTES;
static constexpr size_t OFF_QT    = OFF_VF + QF_BYTES;
static constexpr size_t OFF_KT    = OFF_QT + QT_BYTES;
static constexpr size_t OFF_VT    = OFF_KT + QT_BYTES;
static constexpr size_t OFF_WT    = OFF_VT + QT_BYTES;
static constexpr size_t OFF_WFT   = OFF_WT + WT_BYTES;
static constexpr size_t OFF_BALL  = OFF_WFT + WFT_BYTES;
static constexpr size_t OFF_BF    = OFF_BALL + 1536*4;
static constexpr size_t WS_NEED   = OFF_BF + 64*4;   // ~167 MiB

__device__ __forceinline__ f32x4 mfma16(f16x8 a, f16x8 b, f32x4 c) {
    return __builtin_amdgcn_mfma_f32_16x16x32_f16(a, b, c, 0, 0, 0);
}

// global -> LDS direct copy, 16B per lane. LDS dest must be wave-uniform
// (HW adds lane*16); global src is per-lane.
__device__ __forceinline__ void gl_lds16(const void* g, void* l) {
    __builtin_amdgcn_global_load_lds(
        (const __attribute__((address_space(1))) unsigned int*)(unsigned long long)g,
        (__attribute__((address_space(3))) unsigned int*)(unsigned int)(unsigned long long)l,
        16, 0, 0);
}

// ---------------------------------------------------------------------------
// prep_w: pack six QKV conv weights into wT[tap][n(1536)][c(256)] fp16,
// swapping 3x3 tap indices for the _f (AFAB) weights. Also w_final ->
// wfT[tap][oc(64)][cin(768)], and pack biases.
// ---------------------------------------------------------------------------
__global__ __launch_bounds__(256) void prep_w(
    const float* __restrict__ wqf, const float* __restrict__ wkf, const float* __restrict__ wvf,
    const float* __restrict__ wqt, const float* __restrict__ wkt, const float* __restrict__ wvt,
    const float* __restrict__ wfin,
    const float* __restrict__ bqf, const float* __restrict__ bkf, const float* __restrict__ bvf,
    const float* __restrict__ bqt, const float* __restrict__ bkt, const float* __restrict__ bvt,
    const float* __restrict__ bfin,
    f16* __restrict__ wT, f16* __restrict__ wfT,
    float* __restrict__ biasAll, float* __restrict__ biasF)
{
    int idx = blockIdx.x*256 + threadIdx.x;
    if (idx < 9*1536*256) {
        int tap = idx / (1536*256);
        int r   = idx - tap*(1536*256);
        int n = r >> 8, c = r & 255;
        int dt = tap/3 - 1, df = tap%3 - 1;
        int blk = n >> 8, nl = n & 255;
        const float* w; int kh, kw;
        if (blk < 3) { w = (blk==0) ? wqf : (blk==1) ? wkf : wvf; kh = df+1; kw = dt+1; }
        else         { w = (blk==3) ? wqt : (blk==4) ? wkt : wvt; kh = dt+1; kw = df+1; }
        wT[idx] = (f16)w[((kh*3 + kw)*256 + c)*256 + nl];
    }
    if (idx < 9*64*768) {
        int tap = idx / (64*768);
        int r   = idx - tap*(64*768);
        int oc = r / 768, cin = r - oc*768;
        int dt = tap/3 - 1, df = tap%3 - 1;
        wfT[idx] = (f16)wfin[(((dt+1)*3 + (df+1))*768 + cin)*64 + oc];
    }
    if (idx < 1536) {
        int blk = idx >> 8, nl = idx & 255;
        const float* bb = (blk==0)?bqf:(blk==1)?bkf:(blk==2)?bvf:(blk==3)?bqt:(blk==4)?bkt:bvt;
        biasAll[idx] = bb[nl];
    }
    if (idx < 64) biasF[idx] = bfin[idx];
}

// ---------------------------------------------------------------------------
// prep_x: x (f32) -> xpad (padded fp16) and fused[...][512..767].
// ---------------------------------------------------------------------------
__global__ __launch_bounds__(256) void prep_x(
    const float* __restrict__ x, f16* __restrict__ xpad, f16* __restrict__ fused)
{
    int tid = blockIdx.x*256 + threadIdx.x;     // NPIX*32 exact
    int pix = tid >> 5, c8 = (tid & 31)*8;
    int b = pix / PIXB; int r = pix - b*PIXB;
    int t = r >> 6, f = r & 63;
    const float* src = x + (size_t)pix*256 + c8;
    f16x8 v;
#pragma unroll
    for (int j = 0; j < 8; ++j) v[j] = (f16)src[j];
    size_t pp = (size_t)(b*TP + t + 1)*FP + (f + 1);
    *(f16x8*)(xpad + pp*256 + c8) = v;
    *(f16x8*)(fused + pp*768 + 512 + c8) = v;
}

// ---------------------------------------------------------------------------
// conv_qkv: implicit GEMM, 3-buffer LDS pipeline.
//   M = 31872 (tiles of 128, exact), N = 1536 (tiles of 256 = one output buf
//   each), K = 72 tiles of 32 (9 taps x 8 chunks).
//   512 threads = 8 waves (2 M x 4 N), wave tile 64x64, acc 4x4 f32x4.
//   LDS per buffer: A[128][32] + B[256][32] fp16 = 24 KB; 3 buffers = 72 KB
//   -> 2 blocks/CU. Chunk-XOR swizzle (ch ^= (row>>1)&3) applied on the
//   per-lane GLOBAL source (LDS dest stays linear per global_load_lds rules)
//   and on the ds_read side.
//   Pipeline invariant: per K-tile each wave issues exactly 3 global_load_lds.
//   Loop body: vmcnt(3) [kt's loads landed, kt+1's in flight] -> barrier
//   [publishes kt's data AND proves all waves done reading buf[(kt+2)%3]]
//   -> stage kt+2 -> ds_read kt frags -> 16 MFMA (setprio-wrapped).
// ---------------------------------------------------------------------------
__global__ __launch_bounds__(512, 4) void conv_qkv(
    const f16* __restrict__ xpad, const f16* __restrict__ wT,
    const float* __restrict__ biasAll,
    f16* __restrict__ qf, f16* __restrict__ kf, f16* __restrict__ vf,
    f16* __restrict__ qt, f16* __restrict__ kt_, f16* __restrict__ vt)
{
    __shared__ f16 smem[3*12288];   // 72 KB: per buf A[0,4096) B[4096,12288)

    // --- bijective XCD swizzle (m204), nwg = 1494 = 8*186 + 6 ---
    const int nwgq = 186, nwgr = 6;
    int xcd = blockIdx.x & 7, lin = blockIdx.x >> 3;
    int wg = (xcd < nwgr ? xcd*(nwgq+1) : nwgr*(nwgq+1) + (xcd-nwgr)*nwgq) + lin;
    const int mt = wg / 6;          // 0..248
    const int nt = wg - mt*6;       // 0..5 -> output buffer

    const int l   = threadIdx.x & 63;
    const int wid = threadIdx.x >> 6;
    const int wm = wid >> 2, wn = wid & 3;

    // --- staging source addresses (f16 element offsets) ---
    // A: wave wid stages rows wid*16 + (l>>2), chunk (l&3), swizzled source.
    int rowA = wid*16 + (l >> 2);
    {
    }
    int pA = mt*128 + rowA;
    int bA = pA / PIXB; int rA = pA - bA*PIXB;
    int tA = rA >> 6, fA = rA & 63;
    const int chA = (l & 3) ^ ((rowA >> 1) & 3);
    const int aSrc = ((bA*TP + tA + 1)*FP + (fA + 1))*256 + chA*8;
    // B: two calls, rows j*128 + wid*16 + (l>>2).
    const int rowB = wid*16 + (l >> 2);
    const int chB = (l & 3) ^ ((rowB >> 1) & 3);
    const int bSrc0 = (nt*256 + rowB)*256 + chB*8;
    const int bSrc1 = bSrc0 + 128*256;

    // --- fragment LDS byte... (f16 element) offsets within a buffer ---
    int aOff[4], bOff[4];
#pragma unroll
    for (int mi = 0; mi < 4; ++mi) {
        int row = wm*64 + mi*16 + (l & 15);
        aOff[mi] = row*32 + ((((l >> 4)) ^ ((row >> 1) & 3)) << 3);
    }
#pragma unroll
    for (int ni = 0; ni < 4; ++ni) {
        int row = wn*64 + ni*16 + (l & 15);
        bOff[ni] = 4096 + row*32 + ((((l >> 4)) ^ ((row >> 1) & 3)) << 3);
    }

    f32x4 acc[4][4];
#pragma unroll
    for (int mi = 0; mi < 4; ++mi)
#pragma unroll
        for (int ni = 0; ni < 4; ++ni) acc[mi][ni] = {0.f, 0.f, 0.f, 0.f};

#define QKV_STAGE(KN, NB) do {                                                 \
        int tap_ = (KN) >> 3, kc_ = (KN) & 7;                                  \
        int dt_ = tap_/3 - 1, df_ = tap_ - (tap_/3)*3 - 1;                     \
        int ash_ = (dt_*FP + df_)*256 + kc_*32;                                \
        int bsh_ = tap_*(1536*256) + kc_*32;                                   \
        gl_lds16(xpad + aSrc + ash_, smem + (NB)*12288 + wid*512);             \
        gl_lds16(wT + bSrc0 + bsh_,  smem + (NB)*12288 + 4096 + wid*512);      \
        gl_lds16(wT + bSrc1 + bsh_,  smem + (NB)*12288 + 8192 + wid*512);      \
    } while (0)

#define QKV_STEP(KT, CUR, NB) do {                                             \
        if ((KT) < 71) asm volatile("s_waitcnt vmcnt(3)" ::: "memory");        \
        else           asm volatile("s_waitcnt vmcnt(0)" ::: "memory");        \
        __builtin_amdgcn_s_barrier();                                          \
        __builtin_amdgcn_sched_barrier(0);                                     \
        if ((KT) + 2 < 72) { QKV_STAGE((KT) + 2, NB); }                        \
        {                                                                      \
            const f16* bp_ = smem + (CUR)*12288;                               \
            f16x8 af_[4], bf_[4];                                              \
            _Pragma("unroll")                                                  \
            for (int mi = 0; mi < 4; ++mi) af_[mi] = *(const f16x8*)(bp_ + aOff[mi]); \
            _Pragma("unroll")                                                  \
            for (int ni = 0; ni < 4; ++ni) bf_[ni] = *(const f16x8*)(bp_ + bOff[ni]); \
            __builtin_amdgcn_s_setprio(1);                                     \
            _Pragma("unroll")                                                  \
            for (int mi = 0; mi < 4; ++mi)                                     \
                _Pragma("unroll")                                              \
                for (int ni = 0; ni < 4; ++ni)                                 \
                    acc[mi][ni] = mfma16(af_[mi], bf_[ni], acc[mi][ni]);       \
            __builtin_amdgcn_s_setprio(0);                                     \
        }                                                                      \
    } while (0)

    // prologue: stage K-tiles 0,1 into buffers 0,1
    QKV_STAGE(0, 0);
    QKV_STAGE(1, 1);

    for (int kt = 0; kt < 72; kt += 3) {
        QKV_STEP(kt + 0, 0, 2);
        QKV_STEP(kt + 1, 1, 0);
        QKV_STEP(kt + 2, 2, 1);
    }
#undef QKV_STEP
#undef QKV_STAGE

    // --- epilogue: scatter into attention-friendly layouts ---
    f16* dst = (nt==0)?qf:(nt==1)?kf:(nt==2)?vf:(nt==3)?qt:(nt==4)?kt_:vt;
#pragma unroll
    for (int mi = 0; mi < 4; ++mi) {
#pragma unroll
        for (int rg = 0; rg < 4; ++rg) {
            int row = wm*64 + mi*16 + (l >> 4)*4 + rg;   // D: row=(l>>4)*4+reg
            int p = mt*128 + row;
            int b = p / PIXB; int r = p - b*PIXB;
            int t = r >> 6, f = r & 63;
#pragma unroll
            for (int ni = 0; ni < 4; ++ni) {
                int col = wn*64 + ni*16 + (l & 15);      // D: col=l&15
                int ocg = nt*256 + col;
                float v = acc[mi][ni][rg] + biasAll[ocg];
                int off;
                if (nt < 2)       off = ((b*64 + f)*LPAD + t)*256 + col;
                else if (nt == 2) off = ((b*64 + f)*256 + col)*LPAD + t;
                else if (nt < 5)  off = ((b*T_ + t)*64 + f)*256 + col;
                else              off = ((b*T_ + t)*256 + col)*64 + f;
                dst[off] = (f16)v;
            }
        }
    }
}

// ---------------------------------------------------------------------------
// attn_f: heads (b,f), attention over T (249, padded to 256).
// ---------------------------------------------------------------------------
__global__ __launch_bounds__(256) void attn_f(
    const f16* __restrict__ qf, const f16* __restrict__ kf, const f16* __restrict__ vf,
    const float* __restrict__ alpha, f16* __restrict__ fused)
{
    __shared__ f16 plds[4][16*256];  // wave-private P strips
    const int l = threadIdx.x & 63;
    const int wid = threadIdx.x >> 6;
    const int head = blockIdx.x >> 2;
    const int qb = blockIdx.x & 3;
    const int b = head >> 6, f = head & 63;
    const f16* qh = qf + (size_t)head*LPAD*256;
    const f16* kh = kf + (size_t)head*LPAD*256;
    const f16* vh = vf + (size_t)head*256*LPAD;
    const int qr0 = qb*64 + wid*16;
    f16* pw = &plds[wid][0];

    f16x8 qa[8];
#pragma unroll
    for (int ks = 0; ks < 8; ++ks)
        qa[ks] = *(const f16x8*)(qh + (qr0 + (l & 15))*256 + ks*32 + (l >> 4)*8);

    f32x4 s[16];
#pragma unroll
    for (int nf = 0; nf < 16; ++nf) s[nf] = {0.f, 0.f, 0.f, 0.f};
#pragma unroll
    for (int ks = 0; ks < 8; ++ks)
#pragma unroll
        for (int nf = 0; nf < 16; ++nf) {
            f16x8 bf = *(const f16x8*)(kh + (nf*16 + (l & 15))*256 + ks*32 + (l >> 4)*8);
            s[nf] = mfma16(qa[ks], bf, s[nf]);
        }

    float inv[4];
#pragma unroll
    for (int rg = 0; rg < 4; ++rg) {
        float m = -1e30f;
#pragma unroll
        for (int nf = 0; nf < 16; ++nf)
            if (nf*16 + (l & 15) < T_) m = fmaxf(m, s[nf][rg]);
#pragma unroll
        for (int d = 1; d < 16; d <<= 1) m = fmaxf(m, __shfl_xor(m, d, 64));
        float sum = 0.f;
#pragma unroll
        for (int nf = 0; nf < 16; ++nf) {
            float p = (nf*16 + (l & 15) < T_) ? __expf(s[nf][rg] - m) : 0.f;
            s[nf][rg] = p;   // unnormalized P; 1/sum folded into epilogue
            sum += p;
        }
#pragma unroll
        for (int d = 1; d < 16; d <<= 1) sum += __shfl_xor(sum, d, 64);
        inv[rg] = 1.f / sum;
    }

#pragma unroll
    for (int nf = 0; nf < 16; ++nf)
#pragma unroll
        for (int rg = 0; rg < 4; ++rg) {
            int row = (l >> 4)*4 + rg;
            int col = nf*16 + (l & 15);
            int byte = (row*512 + col*2) ^ ((row & 7) << 4);
            *(f16*)((char*)pw + byte) = (f16)s[nf][rg];
        }

    f32x4 o[16];
#pragma unroll
    for (int nf = 0; nf < 16; ++nf) o[nf] = {0.f, 0.f, 0.f, 0.f};
#pragma unroll
    for (int ks = 0; ks < 8; ++ks) {
        int row = l & 15;
        int cch = ks*4 + (l >> 4);
        int byte = row*512 + ((cch ^ (row & 7)) << 4);
        f16x8 pa = *(const f16x8*)((const char*)pw + byte);
#pragma unroll
        for (int nf = 0; nf < 16; ++nf) {
            f16x8 bf = *(const f16x8*)(vh + (nf*16 + (l & 15))*LPAD + ks*32 + (l >> 4)*8);
            o[nf] = mfma16(pa, bf, o[nf]);
        }
    }

#pragma unroll
    for (int rg = 0; rg < 4; ++rg) {
        int t = qr0 + (l >> 4)*4 + rg;
        if (t < T_) {
#pragma unroll
            for (int nf = 0; nf < 16; ++nf) {
                int c = nf*16 + (l & 15);
                float v = o[nf][rg] * inv[rg] * alpha[((size_t)(b*T_ + t)*64 + f)*256 + c];
                fused[((size_t)(b*TP + t + 1)*FP + (f + 1))*768 + c] = (f16)v;
            }
        }
    }
}

// ---------------------------------------------------------------------------
// attn_t: heads (b,t), attention over F (64, exact).
// ---------------------------------------------------------------------------
__global__ __launch_bounds__(256) void attn_t(
    const f16* __restrict__ qt, const f16* __restrict__ kt, const f16* __restrict__ vt,
    const float* __restrict__ beta, f16* __restrict__ fused)
{
    __shared__ f16 plds[4][16*64];
    const int l = threadIdx.x & 63;
    const int wid = threadIdx.x >> 6;
    const int head = blockIdx.x;        // b*249 + t
    const int b = head / T_, t = head - b*T_;
    const f16* qh = qt + (size_t)head*64*256;
    const f16* kh = kt + (size_t)head*64*256;
    const f16* vh = vt + (size_t)head*256*64;
    const int qr0 = wid*16;
    f16* pw = &plds[wid][0];

    f16x8 qa[8];
#pragma unroll
    for (int ks = 0; ks < 8; ++ks)
        qa[ks] = *(const f16x8*)(qh + (qr0 + (l & 15))*256 + ks*32 + (l >> 4)*8);

    f32x4 s[4];
#pragma unroll
    for (int nf = 0; nf < 4; ++nf) s[nf] = {0.f, 0.f, 0.f, 0.f};
#pragma unroll
    for (int ks = 0; ks < 8; ++ks)
#pragma unroll
        for (int nf = 0; nf < 4; ++nf) {
            f16x8 bf = *(const f16x8*)(kh + (nf*16 + (l & 15))*256 + ks*32 + (l >> 4)*8);
            s[nf] = mfma16(qa[ks], bf, s[nf]);
        }

    float inv[4];
#pragma unroll
    for (int rg = 0; rg < 4; ++rg) {
        float m = -1e30f;
#pragma unroll
        for (int nf = 0; nf < 4; ++nf) m = fmaxf(m, s[nf][rg]);
#pragma unroll
        for (int d = 1; d < 16; d <<= 1) m = fmaxf(m, __shfl_xor(m, d, 64));
        float sum = 0.f;
#pragma unroll
        for (int nf = 0; nf < 4; ++nf) {
            float p = __expf(s[nf][rg] - m);
            s[nf][rg] = p;
            sum += p;
        }
#pragma unroll
        for (int d = 1; d < 16; d <<= 1) sum += __shfl_xor(sum, d, 64);
        inv[rg] = 1.f / sum;
    }

#pragma unroll
    for (int nf = 0; nf < 4; ++nf)
#pragma unroll
        for (int rg = 0; rg < 4; ++rg) {
            int row = (l >> 4)*4 + rg;
            int col = nf*16 + (l & 15);
            int byte = (row*128 + col*2) ^ ((row & 7) << 4);
            *(f16*)((char*)pw + byte) = (f16)s[nf][rg];
        }

    f32x4 o[16];
#pragma unroll
    for (int nf = 0; nf < 16; ++nf) o[nf] = {0.f, 0.f, 0.f, 0.f};
#pragma unroll
    for (int ks = 0; ks < 2; ++ks) {
        int row = l & 15;
        int cch = ks*4 + (l >> 4);
        int byte = row*128 + ((cch ^ (row & 7)) << 4);
        f16x8 pa = *(const f16x8*)((const char*)pw + byte);
#pragma unroll
        for (int nf = 0; nf < 16; ++nf) {
            f16x8 bf = *(const f16x8*)(vh + (nf*16 + (l & 15))*64 + ks*32 + (l >> 4)*8);
            o[nf] = mfma16(pa, bf, o[nf]);
        }
    }

#pragma unroll
    for (int rg = 0; rg < 4; ++rg) {
        int fo = qr0 + (l >> 4)*4 + rg;
#pragma unroll
        for (int nf = 0; nf < 16; ++nf) {
            int c = nf*16 + (l & 15);
            float v = o[nf][rg] * inv[rg] * beta[((size_t)(b*T_ + t)*64 + fo)*256 + c];
            fused[((size_t)(b*TP + t + 1)*FP + (fo + 1))*768 + 256 + c] = (f16)v;
        }
    }
}

// ---------------------------------------------------------------------------
// conv_final: implicit GEMM on fused (padded [B][TP][FP][768]).
// M tile 128 x N 64, K = 9 taps x 768. (unchanged round-1 structure)
// ---------------------------------------------------------------------------
__global__ __launch_bounds__(256) void conv_final(
    const f16* __restrict__ fused, const f16* __restrict__ wfT,
    const float* __restrict__ biasF, float* __restrict__ out)
{
    __shared__ f16 ldsA[128*64];
    __shared__ f16 ldsB[64*64];
    const int l = threadIdx.x & 63;
    const int wid = threadIdx.x >> 6;
    const int mt = blockIdx.x;  // 0..248

    int aBase[4], bBase[2];
#pragma unroll
    for (int i = 0; i < 4; ++i) {
        int row = wid*32 + i*8 + (l >> 3);
        int ch  = (l & 7) ^ (row & 7);
        int p = mt*128 + row;
        int b = p / PIXB; int r = p - b*PIXB;
        int t = r >> 6, f = r & 63;
        aBase[i] = ((b*TP + t + 1)*FP + (f + 1))*768 + ch*8;
    }
#pragma unroll
    for (int i = 0; i < 2; ++i) {
        int row = wid*16 + i*8 + (l >> 3);
        int ch  = (l & 7) ^ (row & 7);
        bBase[i] = row*768 + ch*8;
    }

    f32x4 acc[2][4];
#pragma unroll
    for (int mi = 0; mi < 2; ++mi)
#pragma unroll
        for (int ni = 0; ni < 4; ++ni) acc[mi][ni] = {0.f, 0.f, 0.f, 0.f};

    for (int tap = 0; tap < 9; ++tap) {
        const int dt = tap/3 - 1, df = tap%3 - 1;
        const int ash = (dt*FP + df)*768;
        const f16* wt = wfT + (size_t)tap*64*768;
        for (int kc = 0; kc < 12; ++kc) {
            const int c0 = kc*64;
#pragma unroll
            for (int i = 0; i < 4; ++i)
                gl_lds16(fused + aBase[i] + ash + c0, ldsA + (wid*32 + i*8)*64);
#pragma unroll
            for (int i = 0; i < 2; ++i)
                gl_lds16(wt + bBase[i] + c0, ldsB + (wid*16 + i*8)*64);
            __syncthreads();
#pragma unroll
            for (int kk = 0; kk < 2; ++kk) {
                const int cch = kk*4 + (l >> 4);
                f16x8 af[2], bf[4];
#pragma unroll
                for (int mi = 0; mi < 2; ++mi) {
                    int row = wid*32 + mi*16 + (l & 15);
                    af[mi] = *(const f16x8*)(ldsA + row*64 + ((cch ^ (row & 7)) << 3));
                }
#pragma unroll
                for (int ni = 0; ni < 4; ++ni) {
                    int row = ni*16 + (l & 15);
                    bf[ni] = *(const f16x8*)(ldsB + row*64 + ((cch ^ (row & 7)) << 3));
                }
#pragma unroll
                for (int mi = 0; mi < 2; ++mi)
#pragma unroll
                    for (int ni = 0; ni < 4; ++ni)
                        acc[mi][ni] = mfma16(af[mi], bf[ni], acc[mi][ni]);
            }
            __syncthreads();
        }
    }

#pragma unroll
    for (int mi = 0; mi < 2; ++mi)
#pragma unroll
        for (int rg = 0; rg < 4; ++rg) {
            int row = wid*32 + mi*16 + (l >> 4)*4 + rg;
            int p = mt*128 + row;
#pragma unroll
            for (int ni = 0; ni < 4; ++ni) {
                int oc = ni*16 + (l & 15);
                out[(size_t)p*64 + oc] = acc[mi][ni][rg] + biasF[oc];
            }
        }
}

// ---------------------------------------------------------------------------
extern "C" void kernel_launch(void* const* d_in, const int* in_sizes, int n_in,
                              void* d_out, int out_size, void* d_ws, size_t ws_size,
                              hipStream_t stream) {
    (void)in_sizes; (void)n_in; (void)out_size;
    const float* x    = (const float*)d_in[0];
    const float* wqf  = (const float*)d_in[1];
    const float* bqf  = (const float*)d_in[2];
    const float* wkf  = (const float*)d_in[3];
    const float* bkf  = (const float*)d_in[4];
    const float* wvf  = (const float*)d_in[5];
    const float* bvf  = (const float*)d_in[6];
    const float* wqt  = (const float*)d_in[7];
    const float* bqt  = (const float*)d_in[8];
    const float* wkt  = (const float*)d_in[9];
    const float* bkt  = (const float*)d_in[10];
    const float* wvt  = (const float*)d_in[11];
    const float* bvt  = (const float*)d_in[12];
    const float* wfin = (const float*)d_in[13];
    const float* bfin = (const float*)d_in[14];
    const float* alpha= (const float*)d_in[15];
    const float* beta = (const float*)d_in[16];

    if (ws_size < WS_NEED) return;   // workspace insufficient -> visible failure

    char* ws = (char*)d_ws;
    f16* fused  = (f16*)(ws + OFF_FUSED);
    f16* xpad   = (f16*)(ws + OFF_XPAD);
    f16* qf     = (f16*)(ws + OFF_QF);
    f16* kf     = (f16*)(ws + OFF_KF);
    f16* vf     = (f16*)(ws + OFF_VF);
    f16* qt     = (f16*)(ws + OFF_QT);
    f16* kt     = (f16*)(ws + OFF_KT);
    f16* vt     = (f16*)(ws + OFF_VT);
    f16* wT     = (f16*)(ws + OFF_WT);
    f16* wfT    = (f16*)(ws + OFF_WFT);
    float* bAll = (float*)(ws + OFF_BALL);
    float* bF   = (float*)(ws + OFF_BF);

    // zero padded borders (and v_f pad columns: 0 * P avoids 0*garbage NaN)
    hipMemsetAsync(fused, 0, FUSED_BYTES, stream);
    hipMemsetAsync(xpad,  0, XPAD_BYTES,  stream);
    hipMemsetAsync(vf,    0, QF_BYTES,    stream);

    prep_w<<<dim3((9*1536*256 + 255)/256), dim3(256), 0, stream>>>(
        wqf, wkf, wvf, wqt, wkt, wvt, wfin,
        bqf, bkf, bvf, bqt, bkt, bvt, bfin, wT, wfT, bAll, bF);
    prep_x<<<dim3(NPIX*32/256), dim3(256), 0, stream>>>(x, xpad, fused);
    conv_qkv<<<dim3(1494), dim3(512), 0, stream>>>(xpad, wT, bAll, qf, kf, vf, qt, kt, vt);
    attn_f<<<dim3(512), dim3(256), 0, stream>>>(qf, kf, vf, alpha, fused);
    attn_t<<<dim3(498), dim3(256), 0, stream>>>(qt, kt, vt, beta, fused);
    conv_final<<<dim3(249), dim3(256), 0, stream>>>(fused, wfT, bF, (float*)d_out);
}

// Round 3
// 587.181 us; speedup vs baseline: 1.0858x; 1.0858x over previous
//
#include <hip/hip_runtime.h>

// ---------------------------------------------------------------------------
// ATFA: dual-axis conv-attention, MI355X fp16-MFMA implementation.
// Round 3: revert to round-1's verified 2-barrier staging discipline;
//   conv_qkv: BM=128 BN=256 BK=64, 4 waves (wave tile 64x128), 2 blocks/CU.
//   conv_final: BM=64 (grid 498) BK=128, half the barriers, ~2 blocks/CU.
// ---------------------------------------------------------------------------

typedef _Float16 f16;
typedef _Float16 f16x8 __attribute__((ext_vector_type(8)));
typedef float    f32x4 __attribute__((ext_vector_type(4)));

#define B_   2
#define T_   249
#define F_   64
#define TP   251     // T + 2 (padded)
#define FP   66      // F + 2 (padded)
#define PIXB (T_*F_) // 15936 pixels per batch
#define NPIX (B_*PIXB)
#define LPAD 256     // padded attention length for the T-axis heads

static constexpr size_t FUSED_BYTES = (size_t)B_*TP*FP*768*2;  // 50,890,752
static constexpr size_t XPAD_BYTES  = (size_t)B_*TP*FP*256*2;  // 16,963,584
static constexpr size_t QF_BYTES    = (size_t)B_*64*LPAD*256*2;// 16,777,216
static constexpr size_t QT_BYTES    = (size_t)B_*T_*64*256*2;  // 16,318,464
static constexpr size_t WT_BYTES    = (size_t)9*1536*256*2;    //  7,077,888
static constexpr size_t WFT_BYTES   = (size_t)9*64*768*2;      //    884,736

static constexpr size_t OFF_FUSED = 0;
static constexpr size_t OFF_XPAD  = OFF_FUSED + FUSED_BYTES;
static constexpr size_t OFF_QF    = OFF_XPAD  + XPAD_BYTES;
static constexpr size_t OFF_KF    = OFF_QF + QF_BYTES;
static constexpr size_t OFF_VF    = OFF_KF + QF_BYTES;
static constexpr size_t OFF_QT    = OFF_VF + QF_BYTES;
static constexpr size_t OFF_KT    = OFF_QT + QT_BYTES;
static constexpr size_t OFF_VT    = OFF_KT + QT_BYTES;
static constexpr size_t OFF_WT    = OFF_VT + QT_BYTES;
static constexpr size_t OFF_WFT   = OFF_WT + WT_BYTES;
static constexpr size_t OFF_BALL  = OFF_WFT + WFT_BYTES;
static constexpr size_t OFF_BF    = OFF_BALL + 1536*4;
static constexpr size_t WS_NEED   = OFF_BF + 64*4;   // ~167 MiB

__device__ __forceinline__ f32x4 mfma16(f16x8 a, f16x8 b, f32x4 c) {
    return __builtin_amdgcn_mfma_f32_16x16x32_f16(a, b, c, 0, 0, 0);
}

// global -> LDS direct copy, 16B per lane. LDS dest must be wave-uniform
// (HW adds lane*16); global src is per-lane.
__device__ __forceinline__ void gl_lds16(const void* g, void* l) {
    __builtin_amdgcn_global_load_lds(
        (const __attribute__((address_space(1))) unsigned int*)(unsigned long long)g,
        (__attribute__((address_space(3))) unsigned int*)(unsigned int)(unsigned long long)l,
        16, 0, 0);
}

// ---------------------------------------------------------------------------
// prep_w: pack six QKV conv weights into wT[tap][n(1536)][c(256)] fp16,
// swapping 3x3 tap indices for the _f (AFAB) weights. Also w_final ->
// wfT[tap][oc(64)][cin(768)], and pack biases.
// ---------------------------------------------------------------------------
__global__ __launch_bounds__(256) void prep_w(
    const float* __restrict__ wqf, const float* __restrict__ wkf, const float* __restrict__ wvf,
    const float* __restrict__ wqt, const float* __restrict__ wkt, const float* __restrict__ wvt,
    const float* __restrict__ wfin,
    const float* __restrict__ bqf, const float* __restrict__ bkf, const float* __restrict__ bvf,
    const float* __restrict__ bqt, const float* __restrict__ bkt, const float* __restrict__ bvt,
    const float* __restrict__ bfin,
    f16* __restrict__ wT, f16* __restrict__ wfT,
    float* __restrict__ biasAll, float* __restrict__ biasF)
{
    int idx = blockIdx.x*256 + threadIdx.x;
    if (idx < 9*1536*256) {
        int tap = idx / (1536*256);
        int r   = idx - tap*(1536*256);
        int n = r >> 8, c = r & 255;
        int dt = tap/3 - 1, df = tap%3 - 1;
        int blk = n >> 8, nl = n & 255;
        const float* w; int kh, kw;
        if (blk < 3) { w = (blk==0) ? wqf : (blk==1) ? wkf : wvf; kh = df+1; kw = dt+1; }
        else         { w = (blk==3) ? wqt : (blk==4) ? wkt : wvt; kh = dt+1; kw = df+1; }
        wT[idx] = (f16)w[((kh*3 + kw)*256 + c)*256 + nl];
    }
    if (idx < 9*64*768) {
        int tap = idx / (64*768);
        int r   = idx - tap*(64*768);
        int oc = r / 768, cin = r - oc*768;
        int dt = tap/3 - 1, df = tap%3 - 1;
        wfT[idx] = (f16)wfin[(((dt+1)*3 + (df+1))*768 + cin)*64 + oc];
    }
    if (idx < 1536) {
        int blk = idx >> 8, nl = idx & 255;
        const float* bb = (blk==0)?bqf:(blk==1)?bkf:(blk==2)?bvf:(blk==3)?bqt:(blk==4)?bkt:bvt;
        biasAll[idx] = bb[nl];
    }
    if (idx < 64) biasF[idx] = bfin[idx];
}

// ---------------------------------------------------------------------------
// prep_x: x (f32) -> xpad (padded fp16) and fused[...][512..767].
// ---------------------------------------------------------------------------
__global__ __launch_bounds__(256) void prep_x(
    const float* __restrict__ x, f16* __restrict__ xpad, f16* __restrict__ fused)
{
    int tid = blockIdx.x*256 + threadIdx.x;     // NPIX*32 exact
    int pix = tid >> 5, c8 = (tid & 31)*8;
    int b = pix / PIXB; int r = pix - b*PIXB;
    int t = r >> 6, f = r & 63;
    const float* src = x + (size_t)pix*256 + c8;
    f16x8 v;
#pragma unroll
    for (int j = 0; j < 8; ++j) v[j] = (f16)src[j];
    size_t pp = (size_t)(b*TP + t + 1)*FP + (f + 1);
    *(f16x8*)(xpad + pp*256 + c8) = v;
    *(f16x8*)(fused + pp*768 + 512 + c8) = v;
}

// ---------------------------------------------------------------------------
// conv_qkv: implicit GEMM, round-1 discipline scaled up.
//   M = 31872 (128/tile, exact 249), N = 1536 (256/tile = one output tensor
//   per block), K = 9 taps x 256 in chunks of 64.
//   256 threads = 4 waves (2M x 2N), wave tile 64x128, acc 4x8 f32x4.
//   Per chunk: stage A[128][64] (16KB) + B[256][64] (32KB) via gl_lds16,
//   barrier, 2 kk x 32 MFMA, barrier. Chunk-XOR swizzle (ch ^= row&7) on the
//   per-lane GLOBAL source (LDS dest stays linear) and on the ds_read side
//   (0 bank conflicts verified in rounds 1-2).
//   launch_bounds(256,2): cap 256 regs/wave -> 2 blocks/CU (LDS 48KB).
// ---------------------------------------------------------------------------
__global__ __launch_bounds__(256, 2) void conv_qkv(
    const f16* __restrict__ xpad, const f16* __restrict__ wT,
    const float* __restrict__ biasAll,
    f16* __restrict__ qf, f16* __restrict__ kf, f16* __restrict__ vf,
    f16* __restrict__ qt, f16* __restrict__ kt_, f16* __restrict__ vt)
{
    __shared__ f16 ldsA[128*64];   // 16 KB
    __shared__ f16 ldsB[256*64];   // 32 KB

    // bijective XCD swizzle (m204), nwg = 1494 = 8*186 + 6; contiguous wg
    // ranges per XCD keep same-mt blocks (sharing A) on one XCD's L2.
    const int nwgq = 186, nwgr = 6;
    int xcd = blockIdx.x & 7, lin = blockIdx.x >> 3;
    int wg = (xcd < nwgr ? xcd*(nwgq+1) : nwgr*(nwgq+1) + (xcd-nwgr)*nwgq) + lin;
    const int mt = wg / 6;          // 0..248
    const int nt = wg - mt*6;       // 0..5 -> output tensor

    const int l   = threadIdx.x & 63;
    const int wid = threadIdx.x >> 6;
    const int wm = wid >> 1, wn = wid & 1;

    // staging source bases (f16 element offsets), swizzled chunk on source
    int aSrc[4];
#pragma unroll
    for (int i = 0; i < 4; ++i) {
        int row = i*32 + wid*8 + (l >> 3);
        int ch  = (l & 7) ^ (row & 7);
        int p = mt*128 + row;
        int b = p / PIXB; int r = p - b*PIXB;
        int t = r >> 6, f = r & 63;
        aSrc[i] = ((b*TP + t + 1)*FP + (f + 1))*256 + ch*8;
    }
    int bSrc[8];
#pragma unroll
    for (int j = 0; j < 8; ++j) {
        int row = j*32 + wid*8 + (l >> 3);
        int ch  = (l & 7) ^ (row & 7);
        bSrc[j] = (nt*256 + row)*256 + ch*8;
    }

    // fragment row offsets (element) + per-row swizzle key
    int aRow[4], aSw[4], bRow[8], bSw[8];
#pragma unroll
    for (int mi = 0; mi < 4; ++mi) {
        int row = wm*64 + mi*16 + (l & 15);
        aRow[mi] = row*64; aSw[mi] = row & 7;
    }
#pragma unroll
    for (int ni = 0; ni < 8; ++ni) {
        int row = wn*128 + ni*16 + (l & 15);
        bRow[ni] = row*64; bSw[ni] = row & 7;
    }

    f32x4 acc[4][8];
#pragma unroll
    for (int mi = 0; mi < 4; ++mi)
#pragma unroll
        for (int ni = 0; ni < 8; ++ni) acc[mi][ni] = {0.f, 0.f, 0.f, 0.f};

    for (int tap = 0; tap < 9; ++tap) {
        const int dt = tap/3 - 1, df = tap%3 - 1;
        const int ash = (dt*FP + df)*256;
        const f16* wtap = wT + (size_t)tap*1536*256;
        for (int kc = 0; kc < 4; ++kc) {
            const int c0 = kc*64;
#pragma unroll
            for (int i = 0; i < 4; ++i)
                gl_lds16(xpad + aSrc[i] + ash + c0, ldsA + (i*32 + wid*8)*64);
#pragma unroll
            for (int j = 0; j < 8; ++j)
                gl_lds16(wtap + bSrc[j] + c0, ldsB + (j*32 + wid*8)*64);
            __syncthreads();
#pragma unroll
            for (int kk = 0; kk < 2; ++kk) {
                const int cch = kk*4 + (l >> 4);
                f16x8 af[4], bf[8];
#pragma unroll
                for (int mi = 0; mi < 4; ++mi)
                    af[mi] = *(const f16x8*)(ldsA + aRow[mi] + ((cch ^ aSw[mi]) << 3));
#pragma unroll
                for (int ni = 0; ni < 8; ++ni)
                    bf[ni] = *(const f16x8*)(ldsB + bRow[ni] + ((cch ^ bSw[ni]) << 3));
#pragma unroll
                for (int mi = 0; mi < 4; ++mi)
#pragma unroll
                    for (int ni = 0; ni < 8; ++ni)
                        acc[mi][ni] = mfma16(af[mi], bf[ni], acc[mi][ni]);
            }
            __syncthreads();
        }
    }

    // epilogue: scatter into attention-friendly layouts
    f16* dst = (nt==0)?qf:(nt==1)?kf:(nt==2)?vf:(nt==3)?qt:(nt==4)?kt_:vt;
#pragma unroll
    for (int mi = 0; mi < 4; ++mi) {
#pragma unroll
        for (int rg = 0; rg < 4; ++rg) {
            int row = wm*64 + mi*16 + (l >> 4)*4 + rg;   // D: row=(l>>4)*4+reg
            int p = mt*128 + row;
            int b = p / PIXB; int r = p - b*PIXB;
            int t = r >> 6, f = r & 63;
#pragma unroll
            for (int ni = 0; ni < 8; ++ni) {
                int col = wn*128 + ni*16 + (l & 15);     // D: col=l&15
                float v = acc[mi][ni][rg] + biasAll[nt*256 + col];
                int off;
                if (nt < 2)       off = ((b*64 + f)*LPAD + t)*256 + col;
                else if (nt == 2) off = ((b*64 + f)*256 + col)*LPAD + t;
                else if (nt < 5)  off = ((b*T_ + t)*64 + f)*256 + col;
                else              off = ((b*T_ + t)*256 + col)*64 + f;
                dst[off] = (f16)v;
            }
        }
    }
}

// ---------------------------------------------------------------------------
// attn_f: heads (b,f), attention over T (249, padded to 256).
// ---------------------------------------------------------------------------
__global__ __launch_bounds__(256) void attn_f(
    const f16* __restrict__ qf, const f16* __restrict__ kf, const f16* __restrict__ vf,
    const float* __restrict__ alpha, f16* __restrict__ fused)
{
    __shared__ f16 plds[4][16*256];  // wave-private P strips
    const int l = threadIdx.x & 63;
    const int wid = threadIdx.x >> 6;
    const int head = blockIdx.x >> 2;
    const int qb = blockIdx.x & 3;
    const int b = head >> 6, f = head & 63;
    const f16* qh = qf + (size_t)head*LPAD*256;
    const f16* kh = kf + (size_t)head*LPAD*256;
    const f16* vh = vf + (size_t)head*256*LPAD;
    const int qr0 = qb*64 + wid*16;
    f16* pw = &plds[wid][0];

    f16x8 qa[8];
#pragma unroll
    for (int ks = 0; ks < 8; ++ks)
        qa[ks] = *(const f16x8*)(qh + (qr0 + (l & 15))*256 + ks*32 + (l >> 4)*8);

    f32x4 s[16];
#pragma unroll
    for (int nf = 0; nf < 16; ++nf) s[nf] = {0.f, 0.f, 0.f, 0.f};
#pragma unroll
    for (int ks = 0; ks < 8; ++ks)
#pragma unroll
        for (int nf = 0; nf < 16; ++nf) {
            f16x8 bf = *(const f16x8*)(kh + (nf*16 + (l & 15))*256 + ks*32 + (l >> 4)*8);
            s[nf] = mfma16(qa[ks], bf, s[nf]);
        }

    float inv[4];
#pragma unroll
    for (int rg = 0; rg < 4; ++rg) {
        float m = -1e30f;
#pragma unroll
        for (int nf = 0; nf < 16; ++nf)
            if (nf*16 + (l & 15) < T_) m = fmaxf(m, s[nf][rg]);
#pragma unroll
        for (int d = 1; d < 16; d <<= 1) m = fmaxf(m, __shfl_xor(m, d, 64));
        float sum = 0.f;
#pragma unroll
        for (int nf = 0; nf < 16; ++nf) {
            float p = (nf*16 + (l & 15) < T_) ? __expf(s[nf][rg] - m) : 0.f;
            s[nf][rg] = p;   // unnormalized P; 1/sum folded into epilogue
            sum += p;
        }
#pragma unroll
        for (int d = 1; d < 16; d <<= 1) sum += __shfl_xor(sum, d, 64);
        inv[rg] = 1.f / sum;
    }

#pragma unroll
    for (int nf = 0; nf < 16; ++nf)
#pragma unroll
        for (int rg = 0; rg < 4; ++rg) {
            int row = (l >> 4)*4 + rg;
            int col = nf*16 + (l & 15);
            int byte = (row*512 + col*2) ^ ((row & 7) << 4);
            *(f16*)((char*)pw + byte) = (f16)s[nf][rg];
        }

    f32x4 o[16];
#pragma unroll
    for (int nf = 0; nf < 16; ++nf) o[nf] = {0.f, 0.f, 0.f, 0.f};
#pragma unroll
    for (int ks = 0; ks < 8; ++ks) {
        int row = l & 15;
        int cch = ks*4 + (l >> 4);
        int byte = row*512 + ((cch ^ (row & 7)) << 4);
        f16x8 pa = *(const f16x8*)((const char*)pw + byte);
#pragma unroll
        for (int nf = 0; nf < 16; ++nf) {
            f16x8 bf = *(const f16x8*)(vh + (nf*16 + (l & 15))*LPAD + ks*32 + (l >> 4)*8);
            o[nf] = mfma16(pa, bf, o[nf]);
        }
    }

#pragma unroll
    for (int rg = 0; rg < 4; ++rg) {
        int t = qr0 + (l >> 4)*4 + rg;
        if (t < T_) {
#pragma unroll
            for (int nf = 0; nf < 16; ++nf) {
                int c = nf*16 + (l & 15);
                float v = o[nf][rg] * inv[rg] * alpha[((size_t)(b*T_ + t)*64 + f)*256 + c];
                fused[((size_t)(b*TP + t + 1)*FP + (f + 1))*768 + c] = (f16)v;
            }
        }
    }
}

// ---------------------------------------------------------------------------
// attn_t: heads (b,t), attention over F (64, exact).
// ---------------------------------------------------------------------------
__global__ __launch_bounds__(256) void attn_t(
    const f16* __restrict__ qt, const f16* __restrict__ kt, const f16* __restrict__ vt,
    const float* __restrict__ beta, f16* __restrict__ fused)
{
    __shared__ f16 plds[4][16*64];
    const int l = threadIdx.x & 63;
    const int wid = threadIdx.x >> 6;
    const int head = blockIdx.x;        // b*249 + t
    const int b = head / T_, t = head - b*T_;
    const f16* qh = qt + (size_t)head*64*256;
    const f16* kh = kt + (size_t)head*64*256;
    const f16* vh = vt + (size_t)head*256*64;
    const int qr0 = wid*16;
    f16* pw = &plds[wid][0];

    f16x8 qa[8];
#pragma unroll
    for (int ks = 0; ks < 8; ++ks)
        qa[ks] = *(const f16x8*)(qh + (qr0 + (l & 15))*256 + ks*32 + (l >> 4)*8);

    f32x4 s[4];
#pragma unroll
    for (int nf = 0; nf < 4; ++nf) s[nf] = {0.f, 0.f, 0.f, 0.f};
#pragma unroll
    for (int ks = 0; ks < 8; ++ks)
#pragma unroll
        for (int nf = 0; nf < 4; ++nf) {
            f16x8 bf = *(const f16x8*)(kh + (nf*16 + (l & 15))*256 + ks*32 + (l >> 4)*8);
            s[nf] = mfma16(qa[ks], bf, s[nf]);
        }

    float inv[4];
#pragma unroll
    for (int rg = 0; rg < 4; ++rg) {
        float m = -1e30f;
#pragma unroll
        for (int nf = 0; nf < 4; ++nf) m = fmaxf(m, s[nf][rg]);
#pragma unroll
        for (int d = 1; d < 16; d <<= 1) m = fmaxf(m, __shfl_xor(m, d, 64));
        float sum = 0.f;
#pragma unroll
        for (int nf = 0; nf < 4; ++nf) {
            float p = __expf(s[nf][rg] - m);
            s[nf][rg] = p;
            sum += p;
        }
#pragma unroll
        for (int d = 1; d < 16; d <<= 1) sum += __shfl_xor(sum, d, 64);
        inv[rg] = 1.f / sum;
    }

#pragma unroll
    for (int nf = 0; nf < 4; ++nf)
#pragma unroll
        for (int rg = 0; rg < 4; ++rg) {
            int row = (l >> 4)*4 + rg;
            int col = nf*16 + (l & 15);
            int byte = (row*128 + col*2) ^ ((row & 7) << 4);
            *(f16*)((char*)pw + byte) = (f16)s[nf][rg];
        }

    f32x4 o[16];
#pragma unroll
    for (int nf = 0; nf < 16; ++nf) o[nf] = {0.f, 0.f, 0.f, 0.f};
#pragma unroll
    for (int ks = 0; ks < 2; ++ks) {
        int row = l & 15;
        int cch = ks*4 + (l >> 4);
        int byte = row*128 + ((cch ^ (row & 7)) << 4);
        f16x8 pa = *(const f16x8*)((const char*)pw + byte);
#pragma unroll
        for (int nf = 0; nf < 16; ++nf) {
            f16x8 bf = *(const f16x8*)(vh + (nf*16 + (l & 15))*64 + ks*32 + (l >> 4)*8);
            o[nf] = mfma16(pa, bf, o[nf]);
        }
    }

#pragma unroll
    for (int rg = 0; rg < 4; ++rg) {
        int fo = qr0 + (l >> 4)*4 + rg;
#pragma unroll
        for (int nf = 0; nf < 16; ++nf) {
            int c = nf*16 + (l & 15);
            float v = o[nf][rg] * inv[rg] * beta[((size_t)(b*T_ + t)*64 + fo)*256 + c];
            fused[((size_t)(b*TP + t + 1)*FP + (fo + 1))*768 + 256 + c] = (f16)v;
        }
    }
}

// ---------------------------------------------------------------------------
// conv_final: implicit GEMM on fused (padded [B][TP][FP][768]).
//   M tile 64 (grid 498: one (b,t) with all f per tile), N = 64, K = 9 taps
//   x 768 in chunks of 128 (54 chunks, tap-aligned). 4 waves; wave tile
//   16x64: acc 1x4. LDS A[64][128]+B[64][128] = 32KB. 16-chunk rows with
//   (l&15)^(row&7) source swizzle; ds_read side matches.
// ---------------------------------------------------------------------------
__global__ __launch_bounds__(256, 3) void conv_final(
    const f16* __restrict__ fused, const f16* __restrict__ wfT,
    const float* __restrict__ biasF, float* __restrict__ out)
{
    __shared__ f16 ldsA[64*128];   // 16 KB
    __shared__ f16 ldsB[64*128];   // 16 KB
    const int l = threadIdx.x & 63;
    const int wid = threadIdx.x >> 6;
    const int mt = blockIdx.x;          // 0..497 = (b,t)
    const int b = mt / T_, t = mt - b*T_;

    // staging bases: per load i, rows i*16 + wid*4 + (l>>4), 16B unit (l&15)
    int aSrc[4], bSrc[4];
#pragma unroll
    for (int i = 0; i < 4; ++i) {
        int row = i*16 + wid*4 + (l >> 4);
        int ch  = (l & 15) ^ (row & 7);
        aSrc[i] = ((b*TP + t + 1)*FP + (row + 1))*768 + ch*8;   // f = row
        bSrc[i] = row*768 + ch*8;
    }

    // fragment rows
    int aRowOff, aSwz;
    {
        int row = wid*16 + (l & 15);
        aRowOff = row*128; aSwz = row & 7;
    }
    int bRow[4], bSw[4];
#pragma unroll
    for (int ni = 0; ni < 4; ++ni) {
        int row = ni*16 + (l & 15);
        bRow[ni] = row*128; bSw[ni] = row & 7;
    }

    f32x4 acc[4];
#pragma unroll
    for (int ni = 0; ni < 4; ++ni) acc[ni] = {0.f, 0.f, 0.f, 0.f};

    for (int tap = 0; tap < 9; ++tap) {
        const int dt = tap/3 - 1, df = tap%3 - 1;
        const int ash = (dt*FP + df)*768;
        const f16* wt = wfT + (size_t)tap*64*768;
        for (int kc = 0; kc < 6; ++kc) {
            const int c0 = kc*128;
#pragma unroll
            for (int i = 0; i < 4; ++i) {
                gl_lds16(fused + aSrc[i] + ash + c0, ldsA + (i*16 + wid*4)*128);
                gl_lds16(wt + bSrc[i] + c0,          ldsB + (i*16 + wid*4)*128);
            }
            __syncthreads();
#pragma unroll
            for (int kk = 0; kk < 4; ++kk) {
                const int cch = kk*4 + (l >> 4);     // 0..15
                f16x8 af = *(const f16x8*)(ldsA + aRowOff + ((cch ^ aSwz) << 3));
                f16x8 bf[4];
#pragma unroll
                for (int ni = 0; ni < 4; ++ni)
                    bf[ni] = *(const f16x8*)(ldsB + bRow[ni] + ((cch ^ bSw[ni]) << 3));
#pragma unroll
                for (int ni = 0; ni < 4; ++ni)
                    acc[ni] = mfma16(af, bf[ni], acc[ni]);
            }
            __syncthreads();
        }
    }

#pragma unroll
    for (int rg = 0; rg < 4; ++rg) {
        int f = wid*16 + (l >> 4)*4 + rg;
        int p = mt*64 + f;
#pragma unroll
        for (int ni = 0; ni < 4; ++ni) {
            int oc = ni*16 + (l & 15);
            out[(size_t)p*64 + oc] = acc[ni][rg] + biasF[oc];
        }
    }
}

// ---------------------------------------------------------------------------
extern "C" void kernel_launch(void* const* d_in, const int* in_sizes, int n_in,
                              void* d_out, int out_size, void* d_ws, size_t ws_size,
                              hipStream_t stream) {
    (void)in_sizes; (void)n_in; (void)out_size;
    const float* x    = (const float*)d_in[0];
    const float* wqf  = (const float*)d_in[1];
    const float* bqf  = (const float*)d_in[2];
    const float* wkf  = (const float*)d_in[3];
    const float* bkf  = (const float*)d_in[4];
    const float* wvf  = (const float*)d_in[5];
    const float* bvf  = (const float*)d_in[6];
    const float* wqt  = (const float*)d_in[7];
    const float* bqt  = (const float*)d_in[8];
    const float* wkt  = (const float*)d_in[9];
    const float* bkt  = (const float*)d_in[10];
    const float* wvt  = (const float*)d_in[11];
    const float* bvt  = (const float*)d_in[12];
    const float* wfin = (const float*)d_in[13];
    const float* bfin = (const float*)d_in[14];
    const float* alpha= (const float*)d_in[15];
    const float* beta = (const float*)d_in[16];

    if (ws_size < WS_NEED) return;   // workspace insufficient -> visible failure

    char* ws = (char*)d_ws;
    f16* fused  = (f16*)(ws + OFF_FUSED);
    f16* xpad   = (f16*)(ws + OFF_XPAD);
    f16* qf     = (f16*)(ws + OFF_QF);
    f16* kf     = (f16*)(ws + OFF_KF);
    f16* vf     = (f16*)(ws + OFF_VF);
    f16* qt     = (f16*)(ws + OFF_QT);
    f16* kt     = (f16*)(ws + OFF_KT);
    f16* vt     = (f16*)(ws + OFF_VT);
    f16* wT     = (f16*)(ws + OFF_WT);
    f16* wfT    = (f16*)(ws + OFF_WFT);
    float* bAll = (float*)(ws + OFF_BALL);
    float* bF   = (float*)(ws + OFF_BF);

    // zero padded borders (and v_f pad columns: 0 * P avoids 0*garbage NaN)
    hipMemsetAsync(fused, 0, FUSED_BYTES, stream);
    hipMemsetAsync(xpad,  0, XPAD_BYTES,  stream);
    hipMemsetAsync(vf,    0, QF_BYTES,    stream);

    prep_w<<<dim3((9*1536*256 + 255)/256), dim3(256), 0, stream>>>(
        wqf, wkf, wvf, wqt, wkt, wvt, wfin,
        bqf, bkf, bvf, bqt, bkt, bvt, bfin, wT, wfT, bAll, bF);
    prep_x<<<dim3(NPIX*32/256), dim3(256), 0, stream>>>(x, xpad, fused);
    conv_qkv<<<dim3(1494), dim3(256), 0, stream>>>(xpad, wT, bAll, qf, kf, vf, qt, kt, vt);
    attn_f<<<dim3(512), dim3(256), 0, stream>>>(qf, kf, vf, alpha, fused);
    attn_t<<<dim3(498), dim3(256), 0, stream>>>(qt, kt, vt, beta, fused);
    conv_final<<<dim3(498), dim3(256), 0, stream>>>(fused, wfT, bF, (float*)d_out);
}

// Round 4
// 509.541 us; speedup vs baseline: 1.2512x; 1.1524x over previous
//
#include <hip/hip_runtime.h>

// ---------------------------------------------------------------------------
// ATFA: dual-axis conv-attention, MI355X fp16-MFMA implementation.
// Round 4: r1-verified conv_qkv (BM=128,BN=128,BK=64) + T3-minimum 2-phase
// double-buffer (stage-next-before-compute, ONE barrier per K-chunk);
// r3 conv_final likewise dbuf'd; border-zero kernel replaces 68MB of memsets.
// ---------------------------------------------------------------------------

typedef _Float16 f16;
typedef _Float16 f16x8 __attribute__((ext_vector_type(8)));
typedef float    f32x4 __attribute__((ext_vector_type(4)));

#define B_   2
#define T_   249
#define F_   64
#define TP   251     // T + 2 (padded)
#define FP   66      // F + 2 (padded)
#define PIXB (T_*F_) // 15936 pixels per batch
#define NPIX (B_*PIXB)
#define LPAD 256     // padded attention length for the T-axis heads

static constexpr size_t FUSED_BYTES = (size_t)B_*TP*FP*768*2;  // 50,890,752
static constexpr size_t XPAD_BYTES  = (size_t)B_*TP*FP*256*2;  // 16,963,584
static constexpr size_t QF_BYTES    = (size_t)B_*64*LPAD*256*2;// 16,777,216
static constexpr size_t QT_BYTES    = (size_t)B_*T_*64*256*2;  // 16,318,464
static constexpr size_t WT_BYTES    = (size_t)9*1536*256*2;    //  7,077,888
static constexpr size_t WFT_BYTES   = (size_t)9*64*768*2;      //    884,736

static constexpr size_t OFF_FUSED = 0;
static constexpr size_t OFF_XPAD  = OFF_FUSED + FUSED_BYTES;
static constexpr size_t OFF_QF    = OFF_XPAD  + XPAD_BYTES;
static constexpr size_t OFF_KF    = OFF_QF + QF_BYTES;
static constexpr size_t OFF_VF    = OFF_KF + QF_BYTES;
static constexpr size_t OFF_QT    = OFF_VF + QF_BYTES;
static constexpr size_t OFF_KT    = OFF_QT + QT_BYTES;
static constexpr size_t OFF_VT    = OFF_KT + QT_BYTES;
static constexpr size_t OFF_WT    = OFF_VT + QT_BYTES;
static constexpr size_t OFF_WFT   = OFF_WT + WT_BYTES;
static constexpr size_t OFF_BALL  = OFF_WFT + WFT_BYTES;
static constexpr size_t OFF_BF    = OFF_BALL + 1536*4;
static constexpr size_t WS_NEED   = OFF_BF + 64*4;   // ~167 MiB

__device__ __forceinline__ f32x4 mfma16(f16x8 a, f16x8 b, f32x4 c) {
    return __builtin_amdgcn_mfma_f32_16x16x32_f16(a, b, c, 0, 0, 0);
}

// global -> LDS direct copy, 16B per lane. LDS dest must be wave-uniform
// (HW adds lane*16); global src is per-lane.
__device__ __forceinline__ void gl_lds16(const void* g, void* l) {
    __builtin_amdgcn_global_load_lds(
        (const __attribute__((address_space(1))) unsigned int*)(unsigned long long)g,
        (__attribute__((address_space(3))) unsigned int*)(unsigned int)(unsigned long long)l,
        16, 0, 0);
}

// ---------------------------------------------------------------------------
// prep_w: pack six QKV conv weights into wT[tap][n(1536)][c(256)] fp16,
// swapping 3x3 tap indices for the _f (AFAB) weights. Also w_final ->
// wfT[tap][oc(64)][cin(768)], and pack biases.
// ---------------------------------------------------------------------------
__global__ __launch_bounds__(256) void prep_w(
    const float* __restrict__ wqf, const float* __restrict__ wkf, const float* __restrict__ wvf,
    const float* __restrict__ wqt, const float* __restrict__ wkt, const float* __restrict__ wvt,
    const float* __restrict__ wfin,
    const float* __restrict__ bqf, const float* __restrict__ bkf, const float* __restrict__ bvf,
    const float* __restrict__ bqt, const float* __restrict__ bkt, const float* __restrict__ bvt,
    const float* __restrict__ bfin,
    f16* __restrict__ wT, f16* __restrict__ wfT,
    float* __restrict__ biasAll, float* __restrict__ biasF)
{
    int idx = blockIdx.x*256 + threadIdx.x;
    if (idx < 9*1536*256) {
        int tap = idx / (1536*256);
        int r   = idx - tap*(1536*256);
        int n = r >> 8, c = r & 255;
        int dt = tap/3 - 1, df = tap%3 - 1;
        int blk = n >> 8, nl = n & 255;
        const float* w; int kh, kw;
        if (blk < 3) { w = (blk==0) ? wqf : (blk==1) ? wkf : wvf; kh = df+1; kw = dt+1; }
        else         { w = (blk==3) ? wqt : (blk==4) ? wkt : wvt; kh = dt+1; kw = df+1; }
        wT[idx] = (f16)w[((kh*3 + kw)*256 + c)*256 + nl];
    }
    if (idx < 9*64*768) {
        int tap = idx / (64*768);
        int r   = idx - tap*(64*768);
        int oc = r / 768, cin = r - oc*768;
        int dt = tap/3 - 1, df = tap%3 - 1;
        wfT[idx] = (f16)wfin[(((dt+1)*3 + (df+1))*768 + cin)*64 + oc];
    }
    if (idx < 1536) {
        int blk = idx >> 8, nl = idx & 255;
        const float* bb = (blk==0)?bqf:(blk==1)?bkf:(blk==2)?bvf:(blk==3)?bqt:(blk==4)?bkt:bvt;
        biasAll[idx] = bb[nl];
    }
    if (idx < 64) biasF[idx] = bfin[idx];
}

// ---------------------------------------------------------------------------
// prep_x: x (f32) -> xpad (padded fp16) and fused[...][512..767].
// ---------------------------------------------------------------------------
__global__ __launch_bounds__(256) void prep_x(
    const float* __restrict__ x, f16* __restrict__ xpad, f16* __restrict__ fused)
{
    int tid = blockIdx.x*256 + threadIdx.x;     // NPIX*32 exact
    int pix = tid >> 5, c8 = (tid & 31)*8;
    int b = pix / PIXB; int r = pix - b*PIXB;
    int t = r >> 6, f = r & 63;
    const float* src = x + (size_t)pix*256 + c8;
    f16x8 v;
#pragma unroll
    for (int j = 0; j < 8; ++j) v[j] = (f16)src[j];
    size_t pp = (size_t)(b*TP + t + 1)*FP + (f + 1);
    *(f16x8*)(xpad + pp*256 + c8) = v;
    *(f16x8*)(fused + pp*768 + 512 + c8) = v;
}

// ---------------------------------------------------------------------------
// border_zero: zero only the padded-border pixels of xpad (256ch) and fused
// (768ch). 630 border pixels per batch; block = 2 pixels x 128 threads.
// ---------------------------------------------------------------------------
__global__ __launch_bounds__(256) void border_zero(
    f16* __restrict__ xpad, f16* __restrict__ fused)
{
    int pix = blockIdx.x*2 + (threadIdx.x >> 7);   // 0..1259
    int tl = threadIdx.x & 127;
    int b = pix / 630; int i = pix - b*630;
    int tp, fp;
    if (i < 66)       { tp = 0;   fp = i; }
    else if (i < 132) { tp = 250; fp = i - 66; }
    else { int j = i - 132; tp = 1 + (j >> 1); fp = (j & 1) * 65; }
    size_t pp = (size_t)(b*TP + tp)*FP + fp;
    f16x8 z = {0, 0, 0, 0, 0, 0, 0, 0};
    if (tl < 32) *(f16x8*)(xpad + pp*256 + tl*8) = z;
    if (tl < 96) *(f16x8*)(fused + pp*768 + tl*8) = z;
}

// ---------------------------------------------------------------------------
// conv_qkv: implicit GEMM, r1 geometry + T3-minimum 2-phase double-buffer.
//   M = 31872 (128/tile), N = 1536 (128/tile), K = 36 chunks of 64
//   (9 taps x 4). 4 waves (2Mx2N), wave tile 64x64, acc 4x4 f32x4.
//   LDS: 2 bufs x (A[128][64] + B[128][64]) = 64 KB -> 2 blocks/CU.
//   Chunk-XOR swizzle on per-lane GLOBAL source (LDS dest linear) + matching
//   ds_read swizzle (0 conflicts, verified r1-r3).
//   Loop: STAGE(next,buf^1) -> compute(buf) -> ONE __syncthreads() (its
//   implicit vmcnt(0) drain now overlaps the MFMA block).
// ---------------------------------------------------------------------------
__global__ __launch_bounds__(256) void conv_qkv(
    const f16* __restrict__ xpad, const f16* __restrict__ wT,
    const float* __restrict__ biasAll,
    f16* __restrict__ qf, f16* __restrict__ kf, f16* __restrict__ vf,
    f16* __restrict__ qt, f16* __restrict__ kt_, f16* __restrict__ vt)
{
    __shared__ f16 smem[2][16384];   // per buf: A[0,8192) | B[8192,16384)
    const int l   = threadIdx.x & 63;
    const int wid = threadIdx.x >> 6;

    // bijective XCD swizzle (m204): nwg = 2988 = 8*373 + 4
    const int nwgq = 373, nwgr = 4;
    int xcd = blockIdx.x & 7, lin = blockIdx.x >> 3;
    int wg = (xcd < nwgr ? xcd*(nwgq+1) : nwgr*(nwgq+1) + (xcd-nwgr)*nwgq) + lin;
    const int mt = wg / 12;          // 0..248
    const int nt = wg - mt*12;       // 0..11
    const int wm = wid >> 1, wn = wid & 1;

    // staging source bases (f16 element offsets), swizzled chunk on source
    int aSrc[4], bSrc[4];
#pragma unroll
    for (int i = 0; i < 4; ++i) {
        int row = wid*32 + i*8 + (l >> 3);
        int ch  = (l & 7) ^ (row & 7);
        int p = mt*128 + row;
        int b = p / PIXB; int r = p - b*PIXB;
        int t = r >> 6, f = r & 63;
        aSrc[i] = ((b*TP + t + 1)*FP + (f + 1))*256 + ch*8;
        bSrc[i] = (nt*128 + row)*256 + ch*8;
    }

    // fragment row offsets (f16 elements within a buffer) + swizzle keys
    int aRow[4], aSw[4], bRow[4], bSw[4];
#pragma unroll
    for (int mi = 0; mi < 4; ++mi) {
        int row = wm*64 + mi*16 + (l & 15);
        aRow[mi] = row*64; aSw[mi] = row & 7;
    }
#pragma unroll
    for (int ni = 0; ni < 4; ++ni) {
        int row = wn*64 + ni*16 + (l & 15);
        bRow[ni] = 8192 + row*64; bSw[ni] = row & 7;
    }

    f32x4 acc[4][4];
#pragma unroll
    for (int mi = 0; mi < 4; ++mi)
#pragma unroll
        for (int ni = 0; ni < 4; ++ni) acc[mi][ni] = {0.f, 0.f, 0.f, 0.f};

#define QSTAGE(KN, NB) do {                                                    \
        int tap_ = (KN) >> 2, kc_ = (KN) & 3;                                  \
        int ash_ = ((tap_/3 - 1)*FP + (tap_%3 - 1))*256 + kc_*64;              \
        const f16* wtap_ = wT + (size_t)tap_*(1536*256) + kc_*64;              \
        _Pragma("unroll")                                                      \
        for (int i_ = 0; i_ < 4; ++i_) {                                       \
            gl_lds16(xpad + aSrc[i_] + ash_, &smem[NB][(wid*32 + i_*8)*64]);   \
            gl_lds16(wtap_ + bSrc[i_], &smem[NB][8192 + (wid*32 + i_*8)*64]);  \
        }                                                                      \
    } while (0)

#define QCOMP(NB) do {                                                         \
        _Pragma("unroll")                                                      \
        for (int kk = 0; kk < 2; ++kk) {                                       \
            const int cch = kk*4 + (l >> 4);                                   \
            f16x8 af[4], bf[4];                                                \
            _Pragma("unroll")                                                  \
            for (int mi = 0; mi < 4; ++mi)                                     \
                af[mi] = *(const f16x8*)(&smem[NB][0] + aRow[mi] + ((cch ^ aSw[mi]) << 3)); \
            _Pragma("unroll")                                                  \
            for (int ni = 0; ni < 4; ++ni)                                     \
                bf[ni] = *(const f16x8*)(&smem[NB][0] + bRow[ni] + ((cch ^ bSw[ni]) << 3)); \
            __builtin_amdgcn_s_setprio(1);                                     \
            _Pragma("unroll")                                                  \
            for (int mi = 0; mi < 4; ++mi)                                     \
                _Pragma("unroll")                                              \
                for (int ni = 0; ni < 4; ++ni)                                 \
                    acc[mi][ni] = mfma16(af[mi], bf[ni], acc[mi][ni]);         \
            __builtin_amdgcn_s_setprio(0);                                     \
        }                                                                      \
    } while (0)

    QSTAGE(0, 0);
    __syncthreads();
    for (int kn = 0; kn < 36; kn += 2) {
        if (kn + 1 < 36) QSTAGE(kn + 1, 1);
        QCOMP(0);
        __syncthreads();
        if (kn + 2 < 36) QSTAGE(kn + 2, 0);
        QCOMP(1);
        __syncthreads();
    }
#undef QSTAGE
#undef QCOMP

    // epilogue: scatter into attention-friendly layouts
    const int buf = nt >> 1;   // 0..5 -> qf,kf,vf,qt,kt,vt
    f16* dst = (buf==0)?qf:(buf==1)?kf:(buf==2)?vf:(buf==3)?qt:(buf==4)?kt_:vt;
#pragma unroll
    for (int mi = 0; mi < 4; ++mi) {
#pragma unroll
        for (int rg = 0; rg < 4; ++rg) {
            int row = wm*64 + mi*16 + (l >> 4)*4 + rg;   // D: row=(l>>4)*4+reg
            int p = mt*128 + row;
            int b = p / PIXB; int r = p - b*PIXB;
            int t = r >> 6, f = r & 63;
#pragma unroll
            for (int ni = 0; ni < 4; ++ni) {
                int col = wn*64 + ni*16 + (l & 15);      // D: col=l&15
                int ocg = nt*128 + col;
                int ocl = ocg & 255;
                float v = acc[mi][ni][rg] + biasAll[ocg];
                int off;
                if (buf < 2)       off = ((b*64 + f)*LPAD + t)*256 + ocl;
                else if (buf == 2) off = ((b*64 + f)*256 + ocl)*LPAD + t;
                else if (buf < 5)  off = ((b*T_ + t)*64 + f)*256 + ocl;
                else               off = ((b*T_ + t)*256 + ocl)*64 + f;
                dst[off] = (f16)v;
            }
        }
    }
}

// ---------------------------------------------------------------------------
// attn_f: heads (b,f), attention over T (249, padded to 256).
// ---------------------------------------------------------------------------
__global__ __launch_bounds__(256) void attn_f(
    const f16* __restrict__ qf, const f16* __restrict__ kf, const f16* __restrict__ vf,
    const float* __restrict__ alpha, f16* __restrict__ fused)
{
    __shared__ f16 plds[4][16*256];  // wave-private P strips
    const int l = threadIdx.x & 63;
    const int wid = threadIdx.x >> 6;
    const int head = blockIdx.x >> 2;
    const int qb = blockIdx.x & 3;
    const int b = head >> 6, f = head & 63;
    const f16* qh = qf + (size_t)head*LPAD*256;
    const f16* kh = kf + (size_t)head*LPAD*256;
    const f16* vh = vf + (size_t)head*256*LPAD;
    const int qr0 = qb*64 + wid*16;
    f16* pw = &plds[wid][0];

    f16x8 qa[8];
#pragma unroll
    for (int ks = 0; ks < 8; ++ks)
        qa[ks] = *(const f16x8*)(qh + (qr0 + (l & 15))*256 + ks*32 + (l >> 4)*8);

    f32x4 s[16];
#pragma unroll
    for (int nf = 0; nf < 16; ++nf) s[nf] = {0.f, 0.f, 0.f, 0.f};
#pragma unroll
    for (int ks = 0; ks < 8; ++ks)
#pragma unroll
        for (int nf = 0; nf < 16; ++nf) {
            f16x8 bf = *(const f16x8*)(kh + (nf*16 + (l & 15))*256 + ks*32 + (l >> 4)*8);
            s[nf] = mfma16(qa[ks], bf, s[nf]);
        }

    float inv[4];
#pragma unroll
    for (int rg = 0; rg < 4; ++rg) {
        float m = -1e30f;
#pragma unroll
        for (int nf = 0; nf < 16; ++nf)
            if (nf*16 + (l & 15) < T_) m = fmaxf(m, s[nf][rg]);
#pragma unroll
        for (int d = 1; d < 16; d <<= 1) m = fmaxf(m, __shfl_xor(m, d, 64));
        float sum = 0.f;
#pragma unroll
        for (int nf = 0; nf < 16; ++nf) {
            float p = (nf*16 + (l & 15) < T_) ? __expf(s[nf][rg] - m) : 0.f;
            s[nf][rg] = p;   // unnormalized P; 1/sum folded into epilogue
            sum += p;
        }
#pragma unroll
        for (int d = 1; d < 16; d <<= 1) sum += __shfl_xor(sum, d, 64);
        inv[rg] = 1.f / sum;
    }

#pragma unroll
    for (int nf = 0; nf < 16; ++nf)
#pragma unroll
        for (int rg = 0; rg < 4; ++rg) {
            int row = (l >> 4)*4 + rg;
            int col = nf*16 + (l & 15);
            int byte = (row*512 + col*2) ^ ((row & 7) << 4);
            *(f16*)((char*)pw + byte) = (f16)s[nf][rg];
        }

    f32x4 o[16];
#pragma unroll
    for (int nf = 0; nf < 16; ++nf) o[nf] = {0.f, 0.f, 0.f, 0.f};
#pragma unroll
    for (int ks = 0; ks < 8; ++ks) {
        int row = l & 15;
        int cch = ks*4 + (l >> 4);
        int byte = row*512 + ((cch ^ (row & 7)) << 4);
        f16x8 pa = *(const f16x8*)((const char*)pw + byte);
#pragma unroll
        for (int nf = 0; nf < 16; ++nf) {
            f16x8 bf = *(const f16x8*)(vh + (nf*16 + (l & 15))*LPAD + ks*32 + (l >> 4)*8);
            o[nf] = mfma16(pa, bf, o[nf]);
        }
    }

#pragma unroll
    for (int rg = 0; rg < 4; ++rg) {
        int t = qr0 + (l >> 4)*4 + rg;
        if (t < T_) {
#pragma unroll
            for (int nf = 0; nf < 16; ++nf) {
                int c = nf*16 + (l & 15);
                float v = o[nf][rg] * inv[rg] * alpha[((size_t)(b*T_ + t)*64 + f)*256 + c];
                fused[((size_t)(b*TP + t + 1)*FP + (f + 1))*768 + c] = (f16)v;
            }
        }
    }
}

// ---------------------------------------------------------------------------
// attn_t: heads (b,t), attention over F (64, exact).
// ---------------------------------------------------------------------------
__global__ __launch_bounds__(256) void attn_t(
    const f16* __restrict__ qt, const f16* __restrict__ kt, const f16* __restrict__ vt,
    const float* __restrict__ beta, f16* __restrict__ fused)
{
    __shared__ f16 plds[4][16*64];
    const int l = threadIdx.x & 63;
    const int wid = threadIdx.x >> 6;
    const int head = blockIdx.x;        // b*249 + t
    const int b = head / T_, t = head - b*T_;
    const f16* qh = qt + (size_t)head*64*256;
    const f16* kh = kt + (size_t)head*64*256;
    const f16* vh = vt + (size_t)head*256*64;
    const int qr0 = wid*16;
    f16* pw = &plds[wid][0];

    f16x8 qa[8];
#pragma unroll
    for (int ks = 0; ks < 8; ++ks)
        qa[ks] = *(const f16x8*)(qh + (qr0 + (l & 15))*256 + ks*32 + (l >> 4)*8);

    f32x4 s[4];
#pragma unroll
    for (int nf = 0; nf < 4; ++nf) s[nf] = {0.f, 0.f, 0.f, 0.f};
#pragma unroll
    for (int ks = 0; ks < 8; ++ks)
#pragma unroll
        for (int nf = 0; nf < 4; ++nf) {
            f16x8 bf = *(const f16x8*)(kh + (nf*16 + (l & 15))*256 + ks*32 + (l >> 4)*8);
            s[nf] = mfma16(qa[ks], bf, s[nf]);
        }

    float inv[4];
#pragma unroll
    for (int rg = 0; rg < 4; ++rg) {
        float m = -1e30f;
#pragma unroll
        for (int nf = 0; nf < 4; ++nf) m = fmaxf(m, s[nf][rg]);
#pragma unroll
        for (int d = 1; d < 16; d <<= 1) m = fmaxf(m, __shfl_xor(m, d, 64));
        float sum = 0.f;
#pragma unroll
        for (int nf = 0; nf < 4; ++nf) {
            float p = __expf(s[nf][rg] - m);
            s[nf][rg] = p;
            sum += p;
        }
#pragma unroll
        for (int d = 1; d < 16; d <<= 1) sum += __shfl_xor(sum, d, 64);
        inv[rg] = 1.f / sum;
    }

#pragma unroll
    for (int nf = 0; nf < 4; ++nf)
#pragma unroll
        for (int rg = 0; rg < 4; ++rg) {
            int row = (l >> 4)*4 + rg;
            int col = nf*16 + (l & 15);
            int byte = (row*128 + col*2) ^ ((row & 7) << 4);
            *(f16*)((char*)pw + byte) = (f16)s[nf][rg];
        }

    f32x4 o[16];
#pragma unroll
    for (int nf = 0; nf < 16; ++nf) o[nf] = {0.f, 0.f, 0.f, 0.f};
#pragma unroll
    for (int ks = 0; ks < 2; ++ks) {
        int row = l & 15;
        int cch = ks*4 + (l >> 4);
        int byte = row*128 + ((cch ^ (row & 7)) << 4);
        f16x8 pa = *(const f16x8*)((const char*)pw + byte);
#pragma unroll
        for (int nf = 0; nf < 16; ++nf) {
            f16x8 bf = *(const f16x8*)(vh + (nf*16 + (l & 15))*64 + ks*32 + (l >> 4)*8);
            o[nf] = mfma16(pa, bf, o[nf]);
        }
    }

#pragma unroll
    for (int rg = 0; rg < 4; ++rg) {
        int fo = qr0 + (l >> 4)*4 + rg;
#pragma unroll
        for (int nf = 0; nf < 16; ++nf) {
            int c = nf*16 + (l & 15);
            float v = o[nf][rg] * inv[rg] * beta[((size_t)(b*T_ + t)*64 + fo)*256 + c];
            fused[((size_t)(b*TP + t + 1)*FP + (fo + 1))*768 + 256 + c] = (f16)v;
        }
    }
}

// ---------------------------------------------------------------------------
// conv_final: implicit GEMM on fused (padded [B][TP][FP][768]).
//   M tile 64 (grid 498 = one (b,t), all f), N = 64, K = 54 chunks of 128
//   (9 taps x 6). 4 waves, wave tile 16x64, acc 1x4. T3-minimum 2-phase
//   dbuf: 2 x (A[64][128]+B[64][128]) = 64 KB LDS.
// ---------------------------------------------------------------------------
__global__ __launch_bounds__(256) void conv_final(
    const f16* __restrict__ fused, const f16* __restrict__ wfT,
    const float* __restrict__ biasF, float* __restrict__ out)
{
    __shared__ f16 smem[2][16384];  // per buf: A[0,8192) | B[8192,16384)
    const int l = threadIdx.x & 63;
    const int wid = threadIdx.x >> 6;
    const int mt = blockIdx.x;          // 0..497 = (b,t)
    const int b = mt / T_, t = mt - b*T_;

    int aSrc[4], bSrc[4];
#pragma unroll
    for (int i = 0; i < 4; ++i) {
        int row = i*16 + wid*4 + (l >> 4);
        int ch  = (l & 15) ^ (row & 7);
        aSrc[i] = ((b*TP + t + 1)*FP + (row + 1))*768 + ch*8;   // f = row
        bSrc[i] = row*768 + ch*8;
    }

    int aRowOff, aSwz;
    { int row = wid*16 + (l & 15); aRowOff = row*128; aSwz = row & 7; }
    int bRow[4], bSw[4];
#pragma unroll
    for (int ni = 0; ni < 4; ++ni) {
        int row = ni*16 + (l & 15);
        bRow[ni] = 8192 + row*128; bSw[ni] = row & 7;
    }

    f32x4 acc[4];
#pragma unroll
    for (int ni = 0; ni < 4; ++ni) acc[ni] = {0.f, 0.f, 0.f, 0.f};

#define FSTAGE(KN, NB) do {                                                    \
        int tap_ = (KN) / 6, kc_ = (KN) - ((KN)/6)*6;                          \
        int ash_ = ((tap_/3 - 1)*FP + (tap_%3 - 1))*768 + kc_*128;             \
        const f16* wt_ = wfT + (size_t)tap_*(64*768) + kc_*128;                \
        _Pragma("unroll")                                                      \
        for (int i_ = 0; i_ < 4; ++i_) {                                       \
            gl_lds16(fused + aSrc[i_] + ash_, &smem[NB][(i_*16 + wid*4)*128]); \
            gl_lds16(wt_ + bSrc[i_], &smem[NB][8192 + (i_*16 + wid*4)*128]);   \
        }                                                                      \
    } while (0)

#define FCOMP(NB) do {                                                         \
        _Pragma("unroll")                                                      \
        for (int kk = 0; kk < 4; ++kk) {                                       \
            const int cch = kk*4 + (l >> 4);                                   \
            f16x8 af = *(const f16x8*)(&smem[NB][0] + aRowOff + ((cch ^ aSwz) << 3)); \
            f16x8 bf[4];                                                       \
            _Pragma("unroll")                                                  \
            for (int ni = 0; ni < 4; ++ni)                                     \
                bf[ni] = *(const f16x8*)(&smem[NB][0] + bRow[ni] + ((cch ^ bSw[ni]) << 3)); \
            __builtin_amdgcn_s_setprio(1);                                     \
            _Pragma("unroll")                                                  \
            for (int ni = 0; ni < 4; ++ni)                                     \
                acc[ni] = mfma16(af, bf[ni], acc[ni]);                         \
            __builtin_amdgcn_s_setprio(0);                                     \
        }                                                                      \
    } while (0)

    FSTAGE(0, 0);
    __syncthreads();
    for (int kn = 0; kn < 54; kn += 2) {
        if (kn + 1 < 54) FSTAGE(kn + 1, 1);
        FCOMP(0);
        __syncthreads();
        if (kn + 2 < 54) FSTAGE(kn + 2, 0);
        FCOMP(1);
        __syncthreads();
    }
#undef FSTAGE
#undef FCOMP

#pragma unroll
    for (int rg = 0; rg < 4; ++rg) {
        int f = wid*16 + (l >> 4)*4 + rg;
        int p = mt*64 + f;
#pragma unroll
        for (int ni = 0; ni < 4; ++ni) {
            int oc = ni*16 + (l & 15);
            out[(size_t)p*64 + oc] = acc[ni][rg] + biasF[oc];
        }
    }
}

// ---------------------------------------------------------------------------
extern "C" void kernel_launch(void* const* d_in, const int* in_sizes, int n_in,
                              void* d_out, int out_size, void* d_ws, size_t ws_size,
                              hipStream_t stream) {
    (void)in_sizes; (void)n_in; (void)out_size;
    const float* x    = (const float*)d_in[0];
    const float* wqf  = (const float*)d_in[1];
    const float* bqf  = (const float*)d_in[2];
    const float* wkf  = (const float*)d_in[3];
    const float* bkf  = (const float*)d_in[4];
    const float* wvf  = (const float*)d_in[5];
    const float* bvf  = (const float*)d_in[6];
    const float* wqt  = (const float*)d_in[7];
    const float* bqt  = (const float*)d_in[8];
    const float* wkt  = (const float*)d_in[9];
    const float* bkt  = (const float*)d_in[10];
    const float* wvt  = (const float*)d_in[11];
    const float* bvt  = (const float*)d_in[12];
    const float* wfin = (const float*)d_in[13];
    const float* bfin = (const float*)d_in[14];
    const float* alpha= (const float*)d_in[15];
    const float* beta = (const float*)d_in[16];

    if (ws_size < WS_NEED) return;   // workspace insufficient -> visible failure

    char* ws = (char*)d_ws;
    f16* fused  = (f16*)(ws + OFF_FUSED);
    f16* xpad   = (f16*)(ws + OFF_XPAD);
    f16* qf     = (f16*)(ws + OFF_QF);
    f16* kf     = (f16*)(ws + OFF_KF);
    f16* vf     = (f16*)(ws + OFF_VF);
    f16* qt     = (f16*)(ws + OFF_QT);
    f16* kt     = (f16*)(ws + OFF_KT);
    f16* vt     = (f16*)(ws + OFF_VT);
    f16* wT     = (f16*)(ws + OFF_WT);
    f16* wfT    = (f16*)(ws + OFF_WFT);
    float* bAll = (float*)(ws + OFF_BALL);
    float* bF   = (float*)(ws + OFF_BF);

    // vf must be zero in its pad columns: first call sees arbitrary ws bits
    // (possible NaN) and PV computes 0*V on them. Borders of xpad/fused are
    // zeroed by border_zero (cheaper than 68MB of memset).
    hipMemsetAsync(vf, 0, QF_BYTES, stream);

    border_zero<<<dim3(630), dim3(256), 0, stream>>>(xpad, fused);
    prep_w<<<dim3((9*1536*256 + 255)/256), dim3(256), 0, stream>>>(
        wqf, wkf, wvf, wqt, wkt, wvt, wfin,
        bqf, bkf, bvf, bqt, bkt, bvt, bfin, wT, wfT, bAll, bF);
    prep_x<<<dim3(NPIX*32/256), dim3(256), 0, stream>>>(x, xpad, fused);
    conv_qkv<<<dim3(2988), dim3(256), 0, stream>>>(xpad, wT, bAll, qf, kf, vf, qt, kt, vt);
    attn_f<<<dim3(512), dim3(256), 0, stream>>>(qf, kf, vf, alpha, fused);
    attn_t<<<dim3(498), dim3(256), 0, stream>>>(qt, kt, vt, beta, fused);
    conv_final<<<dim3(498), dim3(256), 0, stream>>>(fused, wfT, bF, (float*)d_out);
}

// Round 5
// 508.807 us; speedup vs baseline: 1.2530x; 1.0014x over previous
//
#include <hip/hip_runtime.h>

// ---------------------------------------------------------------------------
// ATFA: dual-axis conv-attention, MI355X fp16-MFMA implementation.
// Round 5: conv_qkv = BM256/BN128/BK64, 8 waves, ring-3 LDS (144KB) with
// counted s_waitcnt vmcnt(6) (T3/T4, never drain in main loop), XCD-local
// work order (mt-partition per XCD, nt-outer/mt-inner). Rest = round-4.
// ---------------------------------------------------------------------------

typedef _Float16 f16;
typedef _Float16 f16x8 __attribute__((ext_vector_type(8)));
typedef float    f32x4 __attribute__((ext_vector_type(4)));

#define B_   2
#define T_   249
#define F_   64
#define TP   251     // T + 2 (padded)
#define FP   66      // F + 2 (padded)
#define PIXB (T_*F_) // 15936 pixels per batch
#define NPIX (B_*PIXB)
#define LPAD 256     // padded attention length for the T-axis heads

static constexpr size_t FUSED_BYTES = (size_t)B_*TP*FP*768*2;  // 50,890,752
static constexpr size_t XPAD_BYTES  = (size_t)B_*TP*FP*256*2;  // 16,963,584
static constexpr size_t QF_BYTES    = (size_t)B_*64*LPAD*256*2;// 16,777,216
static constexpr size_t QT_BYTES    = (size_t)B_*T_*64*256*2;  // 16,318,464
static constexpr size_t WT_BYTES    = (size_t)9*1536*256*2;    //  7,077,888
static constexpr size_t WFT_BYTES   = (size_t)9*64*768*2;      //    884,736

static constexpr size_t OFF_FUSED = 0;
static constexpr size_t OFF_XPAD  = OFF_FUSED + FUSED_BYTES;
static constexpr size_t OFF_QF    = OFF_XPAD  + XPAD_BYTES;
static constexpr size_t OFF_KF    = OFF_QF + QF_BYTES;
static constexpr size_t OFF_VF    = OFF_KF + QF_BYTES;
static constexpr size_t OFF_QT    = OFF_VF + QF_BYTES;
static constexpr size_t OFF_KT    = OFF_QT + QT_BYTES;
static constexpr size_t OFF_VT    = OFF_KT + QT_BYTES;
static constexpr size_t OFF_WT    = OFF_VT + QT_BYTES;
static constexpr size_t OFF_WFT   = OFF_WT + WT_BYTES;
static constexpr size_t OFF_BALL  = OFF_WFT + WFT_BYTES;
static constexpr size_t OFF_BF    = OFF_BALL + 1536*4;
static constexpr size_t WS_NEED   = OFF_BF + 64*4;   // ~167 MiB

__device__ __forceinline__ f32x4 mfma16(f16x8 a, f16x8 b, f32x4 c) {
    return __builtin_amdgcn_mfma_f32_16x16x32_f16(a, b, c, 0, 0, 0);
}

// global -> LDS direct copy, 16B per lane. LDS dest must be wave-uniform
// (HW adds lane*16); global src is per-lane.
__device__ __forceinline__ void gl_lds16(const void* g, void* l) {
    __builtin_amdgcn_global_load_lds(
        (const __attribute__((address_space(1))) unsigned int*)(unsigned long long)g,
        (__attribute__((address_space(3))) unsigned int*)(unsigned int)(unsigned long long)l,
        16, 0, 0);
}

// ---------------------------------------------------------------------------
// prep_w: pack six QKV conv weights into wT[tap][n(1536)][c(256)] fp16,
// swapping 3x3 tap indices for the _f (AFAB) weights. Also w_final ->
// wfT[tap][oc(64)][cin(768)], and pack biases.
// ---------------------------------------------------------------------------
__global__ __launch_bounds__(256) void prep_w(
    const float* __restrict__ wqf, const float* __restrict__ wkf, const float* __restrict__ wvf,
    const float* __restrict__ wqt, const float* __restrict__ wkt, const float* __restrict__ wvt,
    const float* __restrict__ wfin,
    const float* __restrict__ bqf, const float* __restrict__ bkf, const float* __restrict__ bvf,
    const float* __restrict__ bqt, const float* __restrict__ bkt, const float* __restrict__ bvt,
    const float* __restrict__ bfin,
    f16* __restrict__ wT, f16* __restrict__ wfT,
    float* __restrict__ biasAll, float* __restrict__ biasF)
{
    int idx = blockIdx.x*256 + threadIdx.x;
    if (idx < 9*1536*256) {
        int tap = idx / (1536*256);
        int r   = idx - tap*(1536*256);
        int n = r >> 8, c = r & 255;
        int dt = tap/3 - 1, df = tap%3 - 1;
        int blk = n >> 8, nl = n & 255;
        const float* w; int kh, kw;
        if (blk < 3) { w = (blk==0) ? wqf : (blk==1) ? wkf : wvf; kh = df+1; kw = dt+1; }
        else         { w = (blk==3) ? wqt : (blk==4) ? wkt : wvt; kh = dt+1; kw = df+1; }
        wT[idx] = (f16)w[((kh*3 + kw)*256 + c)*256 + nl];
    }
    if (idx < 9*64*768) {
        int tap = idx / (64*768);
        int r   = idx - tap*(64*768);
        int oc = r / 768, cin = r - oc*768;
        int dt = tap/3 - 1, df = tap%3 - 1;
        wfT[idx] = (f16)wfin[(((dt+1)*3 + (df+1))*768 + cin)*64 + oc];
    }
    if (idx < 1536) {
        int blk = idx >> 8, nl = idx & 255;
        const float* bb = (blk==0)?bqf:(blk==1)?bkf:(blk==2)?bvf:(blk==3)?bqt:(blk==4)?bkt:bvt;
        biasAll[idx] = bb[nl];
    }
    if (idx < 64) biasF[idx] = bfin[idx];
}

// ---------------------------------------------------------------------------
// prep_x: x (f32) -> xpad (padded fp16) and fused[...][512..767].
// ---------------------------------------------------------------------------
__global__ __launch_bounds__(256) void prep_x(
    const float* __restrict__ x, f16* __restrict__ xpad, f16* __restrict__ fused)
{
    int tid = blockIdx.x*256 + threadIdx.x;     // NPIX*32 exact
    int pix = tid >> 5, c8 = (tid & 31)*8;
    int b = pix / PIXB; int r = pix - b*PIXB;
    int t = r >> 6, f = r & 63;
    const float* src = x + (size_t)pix*256 + c8;
    f16x8 v;
#pragma unroll
    for (int j = 0; j < 8; ++j) v[j] = (f16)src[j];
    size_t pp = (size_t)(b*TP + t + 1)*FP + (f + 1);
    *(f16x8*)(xpad + pp*256 + c8) = v;
    *(f16x8*)(fused + pp*768 + 512 + c8) = v;
}

// ---------------------------------------------------------------------------
// border_zero: zero only the padded-border pixels of xpad (256ch) and fused
// (768ch). 630 border pixels per batch; block = 2 pixels x 128 threads.
// ---------------------------------------------------------------------------
__global__ __launch_bounds__(256) void border_zero(
    f16* __restrict__ xpad, f16* __restrict__ fused)
{
    int pix = blockIdx.x*2 + (threadIdx.x >> 7);   // 0..1259
    int tl = threadIdx.x & 127;
    int b = pix / 630; int i = pix - b*630;
    int tp, fp;
    if (i < 66)       { tp = 0;   fp = i; }
    else if (i < 132) { tp = 250; fp = i - 66; }
    else { int j = i - 132; tp = 1 + (j >> 1); fp = (j & 1) * 65; }
    size_t pp = (size_t)(b*TP + tp)*FP + fp;
    f16x8 z = {0, 0, 0, 0, 0, 0, 0, 0};
    if (tl < 32) *(f16x8*)(xpad + pp*256 + tl*8) = z;
    if (tl < 96) *(f16x8*)(fused + pp*768 + tl*8) = z;
}

// ---------------------------------------------------------------------------
// conv_qkv: implicit GEMM, ring-3 counted-vmcnt pipeline.
//   M = 32000 (125 tiles of 256; pixels >= NPIX clamped/guarded),
//   N = 1536 (12 tiles of 128), K = 36 chunks of 64 (9 taps x 4).
//   512 threads = 8 waves (4M x 2N), wave tile 64x64, acc 4x4 f32x4.
//   LDS ring: 3 bufs x (A[256][64] 32KB + B[128][64] 16KB) = 144KB, 1 blk/CU.
//   Per chunk each thread issues 6 gl_lds16 (4 A + 2 B). Steady loop:
//   STAGE(k+2) -> COMP(k) -> s_waitcnt vmcnt(6) [waits chunk k+1 only,
//   k+2 stays in flight] -> s_barrier. Writer safety: stage into buf b
//   happens two barriers after b's last reader. Source-side XOR swizzle
//   (ch ^= row&7) + matching ds_read swizzle: 0 bank conflicts (r1-r4).
//   Work order: XCD x owns a contiguous mt-range; within x, nt-outer /
//   mt-inner => B-tile (590KB) hot per run, A-range L2-resident.
// ---------------------------------------------------------------------------
__global__ __launch_bounds__(512) void conv_qkv(
    const f16* __restrict__ xpad, const f16* __restrict__ wT,
    const float* __restrict__ biasAll,
    f16* __restrict__ qf, f16* __restrict__ kf, f16* __restrict__ vf,
    f16* __restrict__ qt, f16* __restrict__ kt_, f16* __restrict__ vt)
{
    __shared__ f16 smem[3*24576];   // per buf: A[0,16384) | B[16384,24576)

    // XCD-local decode: xcd = bid&7 (round-robin dispatch), lin = temporal
    // order within the XCD. mt-ranges: xcd<5 -> 16 tiles, else 15 (125 total).
    const int xcd = blockIdx.x & 7, lin = blockIdx.x >> 3;
    const int mtcnt  = (xcd < 5) ? 16 : 15;
    if (lin >= 12*mtcnt) return;                 // padded grid tail
    const int mtbase = (xcd < 5) ? xcd*16 : 80 + (xcd - 5)*15;
    int nt, mi;
    if (xcd < 5) { nt = lin >> 4; mi = lin & 15; }
    else         { nt = lin / 15; mi = lin - nt*15; }
    const int mt = mtbase + mi;                  // 0..124

    const int l   = threadIdx.x & 63;
    const int wid = threadIdx.x >> 6;
    const int wm = wid >> 1, wn = wid & 1;

    // staging source bases (f16 element offsets), swizzled chunk on source
    int aSrc[4], bSrc[2];
#pragma unroll
    for (int i = 0; i < 4; ++i) {
        int row = i*64 + wid*8 + (l >> 3);
        int ch  = (l & 7) ^ (row & 7);
        int p = mt*256 + row;
        if (p > NPIX - 1) p = NPIX - 1;          // M padding clamp
        int b = p / PIXB; int r = p - b*PIXB;
        int t = r >> 6, f = r & 63;
        aSrc[i] = ((b*TP + t + 1)*FP + (f + 1))*256 + ch*8;
    }
#pragma unroll
    for (int j = 0; j < 2; ++j) {
        int row = j*64 + wid*8 + (l >> 3);
        int ch  = (l & 7) ^ (row & 7);
        bSrc[j] = (nt*128 + row)*256 + ch*8;
    }

    // fragment element offsets within a buffer + swizzle keys
    int aRow[4], aSw[4], bRow[4], bSw[4];
#pragma unroll
    for (int mi2 = 0; mi2 < 4; ++mi2) {
        int row = wm*64 + mi2*16 + (l & 15);
        aRow[mi2] = row*64; aSw[mi2] = row & 7;
    }
#pragma unroll
    for (int ni = 0; ni < 4; ++ni) {
        int row = wn*64 + ni*16 + (l & 15);
        bRow[ni] = 16384 + row*64; bSw[ni] = row & 7;
    }

    f32x4 acc[4][4];
#pragma unroll
    for (int mi2 = 0; mi2 < 4; ++mi2)
#pragma unroll
        for (int ni = 0; ni < 4; ++ni) acc[mi2][ni] = {0.f, 0.f, 0.f, 0.f};

#define QSTAGE(KN, NB) do {                                                    \
        int tap_ = (KN) >> 2, kc_ = (KN) & 3;                                  \
        int ash_ = ((tap_/3 - 1)*FP + (tap_%3 - 1))*256 + kc_*64;              \
        const f16* wtap_ = wT + (size_t)tap_*(1536*256) + kc_*64;              \
        _Pragma("unroll")                                                      \
        for (int i_ = 0; i_ < 4; ++i_)                                         \
            gl_lds16(xpad + aSrc[i_] + ash_,                                   \
                     &smem[(NB)*24576 + (i_*64 + wid*8)*64]);                  \
        _Pragma("unroll")                                                      \
        for (int j_ = 0; j_ < 2; ++j_)                                         \
            gl_lds16(wtap_ + bSrc[j_],                                         \
                     &smem[(NB)*24576 + 16384 + (j_*64 + wid*8)*64]);          \
    } while (0)

#define QCOMP(NB) do {                                                         \
        _Pragma("unroll")                                                      \
        for (int kk = 0; kk < 2; ++kk) {                                       \
            const int cch = kk*4 + (l >> 4);                                   \
            f16x8 af[4], bf[4];                                                \
            _Pragma("unroll")                                                  \
            for (int mi2 = 0; mi2 < 4; ++mi2)                                  \
                af[mi2] = *(const f16x8*)(&smem[(NB)*24576] + aRow[mi2] + ((cch ^ aSw[mi2]) << 3)); \
            _Pragma("unroll")                                                  \
            for (int ni = 0; ni < 4; ++ni)                                     \
                bf[ni] = *(const f16x8*)(&smem[(NB)*24576] + bRow[ni] + ((cch ^ bSw[ni]) << 3)); \
            __builtin_amdgcn_s_setprio(1);                                     \
            _Pragma("unroll")                                                  \
            for (int mi2 = 0; mi2 < 4; ++mi2)                                  \
                _Pragma("unroll")                                              \
                for (int ni = 0; ni < 4; ++ni)                                 \
                    acc[mi2][ni] = mfma16(af[mi2], bf[ni], acc[mi2][ni]);      \
            __builtin_amdgcn_s_setprio(0);                                     \
        }                                                                      \
    } while (0)

#define VM6  asm volatile("s_waitcnt vmcnt(6)" ::: "memory")
#define VM0  asm volatile("s_waitcnt vmcnt(0)" ::: "memory")
#define BAR  __builtin_amdgcn_s_barrier()

    // prologue: chunks 0,1 in flight; wait chunk 0 only.
    QSTAGE(0, 0);
    QSTAGE(1, 1);
    VM6; BAR;
    // steady state: 11 macro-iters x 3 chunks (0..32), all vmcnt(6)
#pragma unroll 1
    for (int m = 0; m < 11; ++m) {
        const int kn = m*3;
        QSTAGE(kn + 2, 2); QCOMP(0); VM6; BAR;
        QSTAGE(kn + 3, 0); QCOMP(1); VM6; BAR;
        QSTAGE(kn + 4, 1); QCOMP(2); VM6; BAR;
    }
    // epilogue: chunks 33,34,35
    QSTAGE(35, 2); QCOMP(0); VM6; BAR;   // waits chunk 34; 35 in flight
    QCOMP(1);               VM0; BAR;    // waits chunk 35
    QCOMP(2);
#undef QSTAGE
#undef QCOMP
#undef VM6
#undef VM0
#undef BAR

    // epilogue: scatter into attention-friendly layouts
    const int buf = nt >> 1;   // 0..5 -> qf,kf,vf,qt,kt,vt
    f16* dst = (buf==0)?qf:(buf==1)?kf:(buf==2)?vf:(buf==3)?qt:(buf==4)?kt_:vt;
#pragma unroll
    for (int mi2 = 0; mi2 < 4; ++mi2) {
#pragma unroll
        for (int rg = 0; rg < 4; ++rg) {
            int row = wm*64 + mi2*16 + (l >> 4)*4 + rg;  // D: row=(l>>4)*4+reg
            int p = mt*256 + row;
            if (p >= NPIX) continue;
            int b = p / PIXB; int r = p - b*PIXB;
            int t = r >> 6, f = r & 63;
#pragma unroll
            for (int ni = 0; ni < 4; ++ni) {
                int col = wn*64 + ni*16 + (l & 15);      // D: col=l&15
                int ocg = nt*128 + col;
                int ocl = ocg & 255;
                float v = acc[mi2][ni][rg] + biasAll[ocg];
                int off;
                if (buf < 2)       off = ((b*64 + f)*LPAD + t)*256 + ocl;
                else if (buf == 2) off = ((b*64 + f)*256 + ocl)*LPAD + t;
                else if (buf < 5)  off = ((b*T_ + t)*64 + f)*256 + ocl;
                else               off = ((b*T_ + t)*256 + ocl)*64 + f;
                dst[off] = (f16)v;
            }
        }
    }
}

// ---------------------------------------------------------------------------
// attn_f: heads (b,f), attention over T (249, padded to 256).
// ---------------------------------------------------------------------------
__global__ __launch_bounds__(256) void attn_f(
    const f16* __restrict__ qf, const f16* __restrict__ kf, const f16* __restrict__ vf,
    const float* __restrict__ alpha, f16* __restrict__ fused)
{
    __shared__ f16 plds[4][16*256];  // wave-private P strips
    const int l = threadIdx.x & 63;
    const int wid = threadIdx.x >> 6;
    const int head = blockIdx.x >> 2;
    const int qb = blockIdx.x & 3;
    const int b = head >> 6, f = head & 63;
    const f16* qh = qf + (size_t)head*LPAD*256;
    const f16* kh = kf + (size_t)head*LPAD*256;
    const f16* vh = vf + (size_t)head*256*LPAD;
    const int qr0 = qb*64 + wid*16;
    f16* pw = &plds[wid][0];

    f16x8 qa[8];
#pragma unroll
    for (int ks = 0; ks < 8; ++ks)
        qa[ks] = *(const f16x8*)(qh + (qr0 + (l & 15))*256 + ks*32 + (l >> 4)*8);

    f32x4 s[16];
#pragma unroll
    for (int nf = 0; nf < 16; ++nf) s[nf] = {0.f, 0.f, 0.f, 0.f};
#pragma unroll
    for (int ks = 0; ks < 8; ++ks)
#pragma unroll
        for (int nf = 0; nf < 16; ++nf) {
            f16x8 bf = *(const f16x8*)(kh + (nf*16 + (l & 15))*256 + ks*32 + (l >> 4)*8);
            s[nf] = mfma16(qa[ks], bf, s[nf]);
        }

    float inv[4];
#pragma unroll
    for (int rg = 0; rg < 4; ++rg) {
        float m = -1e30f;
#pragma unroll
        for (int nf = 0; nf < 16; ++nf)
            if (nf*16 + (l & 15) < T_) m = fmaxf(m, s[nf][rg]);
#pragma unroll
        for (int d = 1; d < 16; d <<= 1) m = fmaxf(m, __shfl_xor(m, d, 64));
        float sum = 0.f;
#pragma unroll
        for (int nf = 0; nf < 16; ++nf) {
            float p = (nf*16 + (l & 15) < T_) ? __expf(s[nf][rg] - m) : 0.f;
            s[nf][rg] = p;   // unnormalized P; 1/sum folded into epilogue
            sum += p;
        }
#pragma unroll
        for (int d = 1; d < 16; d <<= 1) sum += __shfl_xor(sum, d, 64);
        inv[rg] = 1.f / sum;
    }

#pragma unroll
    for (int nf = 0; nf < 16; ++nf)
#pragma unroll
        for (int rg = 0; rg < 4; ++rg) {
            int row = (l >> 4)*4 + rg;
            int col = nf*16 + (l & 15);
            int byte = (row*512 + col*2) ^ ((row & 7) << 4);
            *(f16*)((char*)pw + byte) = (f16)s[nf][rg];
        }

    f32x4 o[16];
#pragma unroll
    for (int nf = 0; nf < 16; ++nf) o[nf] = {0.f, 0.f, 0.f, 0.f};
#pragma unroll
    for (int ks = 0; ks < 8; ++ks) {
        int row = l & 15;
        int cch = ks*4 + (l >> 4);
        int byte = row*512 + ((cch ^ (row & 7)) << 4);
        f16x8 pa = *(const f16x8*)((const char*)pw + byte);
#pragma unroll
        for (int nf = 0; nf < 16; ++nf) {
            f16x8 bf = *(const f16x8*)(vh + (nf*16 + (l & 15))*LPAD + ks*32 + (l >> 4)*8);
            o[nf] = mfma16(pa, bf, o[nf]);
        }
    }

#pragma unroll
    for (int rg = 0; rg < 4; ++rg) {
        int t = qr0 + (l >> 4)*4 + rg;
        if (t < T_) {
#pragma unroll
            for (int nf = 0; nf < 16; ++nf) {
                int c = nf*16 + (l & 15);
                float v = o[nf][rg] * inv[rg] * alpha[((size_t)(b*T_ + t)*64 + f)*256 + c];
                fused[((size_t)(b*TP + t + 1)*FP + (f + 1))*768 + c] = (f16)v;
            }
        }
    }
}

// ---------------------------------------------------------------------------
// attn_t: heads (b,t), attention over F (64, exact).
// ---------------------------------------------------------------------------
__global__ __launch_bounds__(256) void attn_t(
    const f16* __restrict__ qt, const f16* __restrict__ kt, const f16* __restrict__ vt,
    const float* __restrict__ beta, f16* __restrict__ fused)
{
    __shared__ f16 plds[4][16*64];
    const int l = threadIdx.x & 63;
    const int wid = threadIdx.x >> 6;
    const int head = blockIdx.x;        // b*249 + t
    const int b = head / T_, t = head - b*T_;
    const f16* qh = qt + (size_t)head*64*256;
    const f16* kh = kt + (size_t)head*64*256;
    const f16* vh = vt + (size_t)head*256*64;
    const int qr0 = wid*16;
    f16* pw = &plds[wid][0];

    f16x8 qa[8];
#pragma unroll
    for (int ks = 0; ks < 8; ++ks)
        qa[ks] = *(const f16x8*)(qh + (qr0 + (l & 15))*256 + ks*32 + (l >> 4)*8);

    f32x4 s[4];
#pragma unroll
    for (int nf = 0; nf < 4; ++nf) s[nf] = {0.f, 0.f, 0.f, 0.f};
#pragma unroll
    for (int ks = 0; ks < 8; ++ks)
#pragma unroll
        for (int nf = 0; nf < 4; ++nf) {
            f16x8 bf = *(const f16x8*)(kh + (nf*16 + (l & 15))*256 + ks*32 + (l >> 4)*8);
            s[nf] = mfma16(qa[ks], bf, s[nf]);
        }

    float inv[4];
#pragma unroll
    for (int rg = 0; rg < 4; ++rg) {
        float m = -1e30f;
#pragma unroll
        for (int nf = 0; nf < 4; ++nf) m = fmaxf(m, s[nf][rg]);
#pragma unroll
        for (int d = 1; d < 16; d <<= 1) m = fmaxf(m, __shfl_xor(m, d, 64));
        float sum = 0.f;
#pragma unroll
        for (int nf = 0; nf < 4; ++nf) {
            float p = __expf(s[nf][rg] - m);
            s[nf][rg] = p;
            sum += p;
        }
#pragma unroll
        for (int d = 1; d < 16; d <<= 1) sum += __shfl_xor(sum, d, 64);
        inv[rg] = 1.f / sum;
    }

#pragma unroll
    for (int nf = 0; nf < 4; ++nf)
#pragma unroll
        for (int rg = 0; rg < 4; ++rg) {
            int row = (l >> 4)*4 + rg;
            int col = nf*16 + (l & 15);
            int byte = (row*128 + col*2) ^ ((row & 7) << 4);
            *(f16*)((char*)pw + byte) = (f16)s[nf][rg];
        }

    f32x4 o[16];
#pragma unroll
    for (int nf = 0; nf < 16; ++nf) o[nf] = {0.f, 0.f, 0.f, 0.f};
#pragma unroll
    for (int ks = 0; ks < 2; ++ks) {
        int row = l & 15;
        int cch = ks*4 + (l >> 4);
        int byte = row*128 + ((cch ^ (row & 7)) << 4);
        f16x8 pa = *(const f16x8*)((const char*)pw + byte);
#pragma unroll
        for (int nf = 0; nf < 16; ++nf) {
            f16x8 bf = *(const f16x8*)(vh + (nf*16 + (l & 15))*64 + ks*32 + (l >> 4)*8);
            o[nf] = mfma16(pa, bf, o[nf]);
        }
    }

#pragma unroll
    for (int rg = 0; rg < 4; ++rg) {
        int fo = qr0 + (l >> 4)*4 + rg;
#pragma unroll
        for (int nf = 0; nf < 16; ++nf) {
            int c = nf*16 + (l & 15);
            float v = o[nf][rg] * inv[rg] * beta[((size_t)(b*T_ + t)*64 + fo)*256 + c];
            fused[((size_t)(b*TP + t + 1)*FP + (fo + 1))*768 + 256 + c] = (f16)v;
        }
    }
}

// ---------------------------------------------------------------------------
// conv_final: implicit GEMM on fused (padded [B][TP][FP][768]).
//   M tile 64 (grid 498 = one (b,t), all f), N = 64, K = 54 chunks of 128
//   (9 taps x 6). 4 waves, wave tile 16x64, acc 1x4. 2-phase dbuf (r4).
// ---------------------------------------------------------------------------
__global__ __launch_bounds__(256) void conv_final(
    const f16* __restrict__ fused, const f16* __restrict__ wfT,
    const float* __restrict__ biasF, float* __restrict__ out)
{
    __shared__ f16 smem[2][16384];  // per buf: A[0,8192) | B[8192,16384)
    const int l = threadIdx.x & 63;
    const int wid = threadIdx.x >> 6;
    const int mt = blockIdx.x;          // 0..497 = (b,t)
    const int b = mt / T_, t = mt - b*T_;

    int aSrc[4], bSrc[4];
#pragma unroll
    for (int i = 0; i < 4; ++i) {
        int row = i*16 + wid*4 + (l >> 4);
        int ch  = (l & 15) ^ (row & 7);
        aSrc[i] = ((b*TP + t + 1)*FP + (row + 1))*768 + ch*8;   // f = row
        bSrc[i] = row*768 + ch*8;
    }

    int aRowOff, aSwz;
    { int row = wid*16 + (l & 15); aRowOff = row*128; aSwz = row & 7; }
    int bRow[4], bSw[4];
#pragma unroll
    for (int ni = 0; ni < 4; ++ni) {
        int row = ni*16 + (l & 15);
        bRow[ni] = 8192 + row*128; bSw[ni] = row & 7;
    }

    f32x4 acc[4];
#pragma unroll
    for (int ni = 0; ni < 4; ++ni) acc[ni] = {0.f, 0.f, 0.f, 0.f};

#define FSTAGE(KN, NB) do {                                                    \
        int tap_ = (KN) / 6, kc_ = (KN) - ((KN)/6)*6;                          \
        int ash_ = ((tap_/3 - 1)*FP + (tap_%3 - 1))*768 + kc_*128;             \
        const f16* wt_ = wfT + (size_t)tap_*(64*768) + kc_*128;                \
        _Pragma("unroll")                                                      \
        for (int i_ = 0; i_ < 4; ++i_) {                                       \
            gl_lds16(fused + aSrc[i_] + ash_, &smem[NB][(i_*16 + wid*4)*128]); \
            gl_lds16(wt_ + bSrc[i_], &smem[NB][8192 + (i_*16 + wid*4)*128]);   \
        }                                                                      \
    } while (0)

#define FCOMP(NB) do {                                                         \
        _Pragma("unroll")                                                      \
        for (int kk = 0; kk < 4; ++kk) {                                       \
            const int cch = kk*4 + (l >> 4);                                   \
            f16x8 af = *(const f16x8*)(&smem[NB][0] + aRowOff + ((cch ^ aSwz) << 3)); \
            f16x8 bf[4];                                                       \
            _Pragma("unroll")                                                  \
            for (int ni = 0; ni < 4; ++ni)                                     \
                bf[ni] = *(const f16x8*)(&smem[NB][0] + bRow[ni] + ((cch ^ bSw[ni]) << 3)); \
            __builtin_amdgcn_s_setprio(1);                                     \
            _Pragma("unroll")                                                  \
            for (int ni = 0; ni < 4; ++ni)                                     \
                acc[ni] = mfma16(af, bf[ni], acc[ni]);                         \
            __builtin_amdgcn_s_setprio(0);                                     \
        }                                                                      \
    } while (0)

    FSTAGE(0, 0);
    __syncthreads();
    for (int kn = 0; kn < 54; kn += 2) {
        if (kn + 1 < 54) FSTAGE(kn + 1, 1);
        FCOMP(0);
        __syncthreads();
        if (kn + 2 < 54) FSTAGE(kn + 2, 0);
        FCOMP(1);
        __syncthreads();
    }
#undef FSTAGE
#undef FCOMP

#pragma unroll
    for (int rg = 0; rg < 4; ++rg) {
        int f = wid*16 + (l >> 4)*4 + rg;
        int p = mt*64 + f;
#pragma unroll
        for (int ni = 0; ni < 4; ++ni) {
            int oc = ni*16 + (l & 15);
            out[(size_t)p*64 + oc] = acc[ni][rg] + biasF[oc];
        }
    }
}

// ---------------------------------------------------------------------------
extern "C" void kernel_launch(void* const* d_in, const int* in_sizes, int n_in,
                              void* d_out, int out_size, void* d_ws, size_t ws_size,
                              hipStream_t stream) {
    (void)in_sizes; (void)n_in; (void)out_size;
    const float* x    = (const float*)d_in[0];
    const float* wqf  = (const float*)d_in[1];
    const float* bqf  = (const float*)d_in[2];
    const float* wkf  = (const float*)d_in[3];
    const float* bkf  = (const float*)d_in[4];
    const float* wvf  = (const float*)d_in[5];
    const float* bvf  = (const float*)d_in[6];
    const float* wqt  = (const float*)d_in[7];
    const float* bqt  = (const float*)d_in[8];
    const float* wkt  = (const float*)d_in[9];
    const float* bkt  = (const float*)d_in[10];
    const float* wvt  = (const float*)d_in[11];
    const float* bvt  = (const float*)d_in[12];
    const float* wfin = (const float*)d_in[13];
    const float* bfin = (const float*)d_in[14];
    const float* alpha= (const float*)d_in[15];
    const float* beta = (const float*)d_in[16];

    if (ws_size < WS_NEED) return;   // workspace insufficient -> visible failure

    char* ws = (char*)d_ws;
    f16* fused  = (f16*)(ws + OFF_FUSED);
    f16* xpad   = (f16*)(ws + OFF_XPAD);
    f16* qf     = (f16*)(ws + OFF_QF);
    f16* kf     = (f16*)(ws + OFF_KF);
    f16* vf     = (f16*)(ws + OFF_VF);
    f16* qt     = (f16*)(ws + OFF_QT);
    f16* kt     = (f16*)(ws + OFF_KT);
    f16* vt     = (f16*)(ws + OFF_VT);
    f16* wT     = (f16*)(ws + OFF_WT);
    f16* wfT    = (f16*)(ws + OFF_WFT);
    float* bAll = (float*)(ws + OFF_BALL);
    float* bF   = (float*)(ws + OFF_BF);

    // vf must be zero in its pad columns: first call sees arbitrary ws bits
    // (possible NaN) and PV computes 0*V on them.
    hipMemsetAsync(vf, 0, QF_BYTES, stream);

    border_zero<<<dim3(630), dim3(256), 0, stream>>>(xpad, fused);
    prep_w<<<dim3((9*1536*256 + 255)/256), dim3(256), 0, stream>>>(
        wqf, wkf, wvf, wqt, wkt, wvt, wfin,
        bqf, bkf, bvf, bqt, bkt, bvt, bfin, wT, wfT, bAll, bF);
    prep_x<<<dim3(NPIX*32/256), dim3(256), 0, stream>>>(x, xpad, fused);
    conv_qkv<<<dim3(1536), dim3(512), 0, stream>>>(xpad, wT, bAll, qf, kf, vf, qt, kt, vt);
    attn_f<<<dim3(512), dim3(256), 0, stream>>>(qf, kf, vf, alpha, fused);
    attn_t<<<dim3(498), dim3(256), 0, stream>>>(qt, kt, vt, beta, fused);
    conv_final<<<dim3(498), dim3(256), 0, stream>>>(fused, wfT, bF, (float*)d_out);
}

// Round 6
// 496.249 us; speedup vs baseline: 1.2847x; 1.0253x over previous
//
#include <hip/hip_runtime.h>

// ---------------------------------------------------------------------------
// ATFA: dual-axis conv-attention, MI355X fp16-MFMA implementation.
// Round 6: conv_qkv rebuilt around A-halo reuse: stage the 6-trow xpad halo
// once per 64-ch chunk (linear in xpad position space!) and serve all 9 taps
// from LDS; BN=256 (one output tensor/block). DMA drops from 256 to ~75
// bytes/MFMA. 2-phase B double-buffer (r4-proven), XCD-local order (r5).
// ---------------------------------------------------------------------------

typedef _Float16 f16;
typedef _Float16 f16x8 __attribute__((ext_vector_type(8)));
typedef float    f32x4 __attribute__((ext_vector_type(4)));

#define B_   2
#define T_   249
#define F_   64
#define TP   251     // T + 2 (padded)
#define FP   66      // F + 2 (padded)
#define PIXB (T_*F_) // 15936 pixels per batch
#define NPIX (B_*PIXB)
#define LPAD 256     // padded attention length for the T-axis heads
#define XPOS (B_*TP*FP)   // 33132 xpad positions

static constexpr size_t FUSED_BYTES = (size_t)B_*TP*FP*768*2;  // 50,890,752
static constexpr size_t XPAD_BYTES  = (size_t)B_*TP*FP*256*2;  // 16,963,584
static constexpr size_t QF_BYTES    = (size_t)B_*64*LPAD*256*2;// 16,777,216
static constexpr size_t QT_BYTES    = (size_t)B_*T_*64*256*2;  // 16,318,464
static constexpr size_t WT_BYTES    = (size_t)9*1536*256*2;    //  7,077,888
static constexpr size_t WFT_BYTES   = (size_t)9*64*768*2;      //    884,736

static constexpr size_t OFF_FUSED = 0;
static constexpr size_t OFF_XPAD  = OFF_FUSED + FUSED_BYTES;
static constexpr size_t OFF_QF    = OFF_XPAD  + XPAD_BYTES;
static constexpr size_t OFF_KF    = OFF_QF + QF_BYTES;
static constexpr size_t OFF_VF    = OFF_KF + QF_BYTES;
static constexpr size_t OFF_QT    = OFF_VF + QF_BYTES;
static constexpr size_t OFF_KT    = OFF_QT + QT_BYTES;
static constexpr size_t OFF_VT    = OFF_KT + QT_BYTES;
static constexpr size_t OFF_WT    = OFF_VT + QT_BYTES;
static constexpr size_t OFF_WFT   = OFF_WT + WT_BYTES;
static constexpr size_t OFF_BALL  = OFF_WFT + WFT_BYTES;
static constexpr size_t OFF_BF    = OFF_BALL + 1536*4;
static constexpr size_t WS_NEED   = OFF_BF + 64*4;   // ~167 MiB

__device__ __forceinline__ f32x4 mfma16(f16x8 a, f16x8 b, f32x4 c) {
    return __builtin_amdgcn_mfma_f32_16x16x32_f16(a, b, c, 0, 0, 0);
}

// global -> LDS direct copy, 16B per lane. LDS dest must be wave-uniform
// (HW adds lane*16); global src is per-lane.
__device__ __forceinline__ void gl_lds16(const void* g, void* l) {
    __builtin_amdgcn_global_load_lds(
        (const __attribute__((address_space(1))) unsigned int*)(unsigned long long)g,
        (__attribute__((address_space(3))) unsigned int*)(unsigned int)(unsigned long long)l,
        16, 0, 0);
}

// ---------------------------------------------------------------------------
// prep_w: pack six QKV conv weights into wT[tap][n(1536)][c(256)] fp16,
// swapping 3x3 tap indices for the _f (AFAB) weights. Also w_final ->
// wfT[tap][oc(64)][cin(768)], and pack biases.
// ---------------------------------------------------------------------------
__global__ __launch_bounds__(256) void prep_w(
    const float* __restrict__ wqf, const float* __restrict__ wkf, const float* __restrict__ wvf,
    const float* __restrict__ wqt, const float* __restrict__ wkt, const float* __restrict__ wvt,
    const float* __restrict__ wfin,
    const float* __restrict__ bqf, const float* __restrict__ bkf, const float* __restrict__ bvf,
    const float* __restrict__ bqt, const float* __restrict__ bkt, const float* __restrict__ bvt,
    const float* __restrict__ bfin,
    f16* __restrict__ wT, f16* __restrict__ wfT,
    float* __restrict__ biasAll, float* __restrict__ biasF)
{
    int idx = blockIdx.x*256 + threadIdx.x;
    if (idx < 9*1536*256) {
        int tap = idx / (1536*256);
        int r   = idx - tap*(1536*256);
        int n = r >> 8, c = r & 255;
        int dt = tap/3 - 1, df = tap%3 - 1;
        int blk = n >> 8, nl = n & 255;
        const float* w; int kh, kw;
        if (blk < 3) { w = (blk==0) ? wqf : (blk==1) ? wkf : wvf; kh = df+1; kw = dt+1; }
        else         { w = (blk==3) ? wqt : (blk==4) ? wkt : wvt; kh = dt+1; kw = df+1; }
        wT[idx] = (f16)w[((kh*3 + kw)*256 + c)*256 + nl];
    }
    if (idx < 9*64*768) {
        int tap = idx / (64*768);
        int r   = idx - tap*(64*768);
        int oc = r / 768, cin = r - oc*768;
        int dt = tap/3 - 1, df = tap%3 - 1;
        wfT[idx] = (f16)wfin[(((dt+1)*3 + (df+1))*768 + cin)*64 + oc];
    }
    if (idx < 1536) {
        int blk = idx >> 8, nl = idx & 255;
        const float* bb = (blk==0)?bqf:(blk==1)?bkf:(blk==2)?bvf:(blk==3)?bqt:(blk==4)?bkt:bvt;
        biasAll[idx] = bb[nl];
    }
    if (idx < 64) biasF[idx] = bfin[idx];
}

// ---------------------------------------------------------------------------
// prep_x: x (f32) -> xpad (padded fp16) and fused[...][512..767].
// ---------------------------------------------------------------------------
__global__ __launch_bounds__(256) void prep_x(
    const float* __restrict__ x, f16* __restrict__ xpad, f16* __restrict__ fused)
{
    int tid = blockIdx.x*256 + threadIdx.x;     // NPIX*32 exact
    int pix = tid >> 5, c8 = (tid & 31)*8;
    int b = pix / PIXB; int r = pix - b*PIXB;
    int t = r >> 6, f = r & 63;
    const float* src = x + (size_t)pix*256 + c8;
    f16x8 v;
#pragma unroll
    for (int j = 0; j < 8; ++j) v[j] = (f16)src[j];
    size_t pp = (size_t)(b*TP + t + 1)*FP + (f + 1);
    *(f16x8*)(xpad + pp*256 + c8) = v;
    *(f16x8*)(fused + pp*768 + 512 + c8) = v;
}

// ---------------------------------------------------------------------------
// border_zero: zero only the padded-border pixels of xpad (256ch) and fused
// (768ch). 630 border pixels per batch; block = 2 pixels x 128 threads.
// ---------------------------------------------------------------------------
__global__ __launch_bounds__(256) void border_zero(
    f16* __restrict__ xpad, f16* __restrict__ fused)
{
    int pix = blockIdx.x*2 + (threadIdx.x >> 7);   // 0..1259
    int tl = threadIdx.x & 127;
    int b = pix / 630; int i = pix - b*630;
    int tp, fp;
    if (i < 66)       { tp = 0;   fp = i; }
    else if (i < 132) { tp = 250; fp = i - 66; }
    else { int j = i - 132; tp = 1 + (j >> 1); fp = (j & 1) * 65; }
    size_t pp = (size_t)(b*TP + tp)*FP + fp;
    f16x8 z = {0, 0, 0, 0, 0, 0, 0, 0};
    if (tl < 32) *(f16x8*)(xpad + pp*256 + tl*8) = z;
    if (tl < 96) *(f16x8*)(fused + pp*768 + tl*8) = z;
}

// ---------------------------------------------------------------------------
// conv_qkv: implicit GEMM with A-halo reuse.
//   Tiles: mt in [0,126) = batch-aligned 4-trow (256-pixel) tiles
//   (63/batch; last tile of each batch has 1 valid trow). nt in [0,6) = one
//   full output tensor (256 channels). K: 4 ch-chunks x 9 taps.
//   512 threads = 8 waves (2M x 4N), wave tile 128x64, acc 8x4 f32x4.
//   LDS: halo [448 pos][64ch] 56KB (single buf, re-staged per ch-chunk;
//   serves all 9 taps via pos shift dt*66+df) + B dbuf 2x[256][64] 64KB.
//   Per tap-iter: prefetch next B (8KB/wave... 32KB/block), compute 64
//   MFMA/wave, ONE __syncthreads (r4-proven 2-phase). Source-side XOR
//   swizzle keyed on LDS row/pos (0 bank conflicts, r1-r5).
//   Work order: XCD-local (mt partition per XCD, nt-outer) for L2 reuse.
// ---------------------------------------------------------------------------
__global__ __launch_bounds__(512, 2) void conv_qkv(
    const f16* __restrict__ xpad, const f16* __restrict__ wT,
    const float* __restrict__ biasAll,
    f16* __restrict__ qf, f16* __restrict__ kf, f16* __restrict__ vf,
    f16* __restrict__ qt, f16* __restrict__ kt_, f16* __restrict__ vt)
{
    __shared__ f16 smemH[448*64];      // 56 KB halo
    __shared__ f16 smemB[2][256*64];   // 64 KB B double-buffer

    // XCD-local decode: xcd = bid&7 (round-robin), lin = order within XCD.
    // mt partition: xcd<6 -> 16 tiles, else 15 (126 total). nt-outer.
    const int xcd = blockIdx.x & 7, lin = blockIdx.x >> 3;
    const int mtcnt = (xcd < 6) ? 16 : 15;
    if (lin >= 6*mtcnt) return;                  // padded grid tail
    const int mtbase = (xcd < 6) ? xcd*16 : 96 + (xcd - 6)*15;
    const int nt = lin / mtcnt;
    const int mt = mtbase + (lin - nt*mtcnt);    // 0..125

    const int bb_ = mt / 63;                     // batch
    const int t0  = (mt - bb_*63) * 4;           // first t-row of tile
    const int Gs66 = (bb_*TP + t0) * 66;         // halo start in xpad pos space

    const int l   = threadIdx.x & 63;
    const int wid = threadIdx.x >> 6;
    const int wm = wid >> 2, wn = wid & 3;       // 2M x 4N

    // --- halo staging: 7 rounds, 448 pos x 8 ch slots, clamped source ---
    int hOff[7];
#pragma unroll
    for (int j = 0; j < 7; ++j) {
        int pos = j*64 + wid*8 + (l >> 3);       // 0..447
        int ps = pos;
        if (ps > 395) ps = 395;                  // halo = 6*66 = 396 positions
        int pmax = (XPOS - 1) - Gs66/1;          // clamp to xpad end
        { int pm = XPOS - 1 - (bb_*TP + t0)*66; if (ps > pm) ps = pm; }
        (void)pmax;
        int ch = (l & 7) ^ (ps & 7);
        hOff[j] = (Gs66 + ps)*256 + ch*8;
    }
    // --- B staging: 4 rounds, 256 rows x 8 ch ---
    int bSrc[4];
#pragma unroll
    for (int j = 0; j < 4; ++j) {
        int row = j*64 + wid*8 + (l >> 3);
        int ch = (l & 7) ^ (row & 7);
        bSrc[j] = (nt*256 + row)*256 + ch*8;
    }

    // --- fragment offsets ---
    int pos00[8];                                // halo pos for tap (0,0)
#pragma unroll
    for (int m = 0; m < 8; ++m) {
        int r = wm*128 + m*16 + (l & 15);
        pos00[m] = ((r >> 6) + 1)*66 + (r & 63) + 1;
    }
    int bRow[4], bSw[4];
#pragma unroll
    for (int n = 0; n < 4; ++n) {
        int row = wn*64 + n*16 + (l & 15);
        bRow[n] = row*64; bSw[n] = row & 7;
    }

    f32x4 acc[8][4];
#pragma unroll
    for (int m = 0; m < 8; ++m)
#pragma unroll
        for (int n = 0; n < 4; ++n) acc[m][n] = {0.f, 0.f, 0.f, 0.f};

#define HSTAGE(C) do {                                                         \
        _Pragma("unroll")                                                      \
        for (int j_ = 0; j_ < 7; ++j_)                                         \
            gl_lds16(xpad + hOff[j_] + (C)*64,                                 \
                     smemH + (j_*512 + wid*64)*8);                             \
    } while (0)

#define BSTAGE(TAP, C, NB) do {                                                \
        const f16* wt_ = wT + (size_t)(TAP)*(1536*256) + (C)*64;               \
        _Pragma("unroll")                                                      \
        for (int j_ = 0; j_ < 4; ++j_)                                         \
            gl_lds16(wt_ + bSrc[j_], &smemB[NB][(j_*512 + wid*64)*8]);         \
    } while (0)

#define QCOMP(NB, TAPOFF) do {                                                 \
        int pos_[8];                                                           \
        _Pragma("unroll")                                                      \
        for (int m = 0; m < 8; ++m) pos_[m] = pos00[m] + (TAPOFF);             \
        _Pragma("unroll")                                                      \
        for (int kk = 0; kk < 2; ++kk) {                                       \
            const int cch = kk*4 + (l >> 4);                                   \
            f16x8 af[8], bf[4];                                                \
            _Pragma("unroll")                                                  \
            for (int m = 0; m < 8; ++m)                                        \
                af[m] = *(const f16x8*)(smemH + pos_[m]*64 + ((cch ^ (pos_[m] & 7)) << 3)); \
            _Pragma("unroll")                                                  \
            for (int n = 0; n < 4; ++n)                                        \
                bf[n] = *(const f16x8*)(&smemB[NB][0] + bRow[n] + ((cch ^ bSw[n]) << 3)); \
            __builtin_amdgcn_s_setprio(1);                                     \
            _Pragma("unroll")                                                  \
            for (int m = 0; m < 8; ++m)                                        \
                _Pragma("unroll")                                              \
                for (int n = 0; n < 4; ++n)                                    \
                    acc[m][n] = mfma16(af[m], bf[n], acc[m][n]);               \
            __builtin_amdgcn_s_setprio(0);                                     \
        }                                                                      \
    } while (0)

    int buf = 0;
    HSTAGE(0);
    BSTAGE(0, 0, 0);
    __syncthreads();
    for (int c = 0; c < 4; ++c) {
        for (int tap = 0; tap < 9; ++tap) {
            // prefetch next B tile into the other buffer
            if (tap < 8)      BSTAGE(tap + 1, c, buf ^ 1);
            else if (c < 3)   BSTAGE(0, c + 1, buf ^ 1);
            const int dt = tap/3 - 1, df = tap - (tap/3)*3 - 1;
            QCOMP(buf, dt*66 + df);
            __syncthreads();
            buf ^= 1;
        }
        if (c < 3) {                 // re-stage halo for next ch-chunk
            HSTAGE(c + 1);
            __syncthreads();
        }
    }
#undef HSTAGE
#undef BSTAGE
#undef QCOMP

    // --- epilogue: scatter into attention-friendly layouts ---
    f16* dst = (nt==0)?qf:(nt==1)?kf:(nt==2)?vf:(nt==3)?qt:(nt==4)?kt_:vt;
#pragma unroll
    for (int m = 0; m < 8; ++m) {
#pragma unroll
        for (int rg = 0; rg < 4; ++rg) {
            int row = wm*128 + m*16 + (l >> 4)*4 + rg;   // D: row=(l>>4)*4+reg
            int t = t0 + (row >> 6), f = row & 63;
            if (t <= 248) {
#pragma unroll
                for (int n = 0; n < 4; ++n) {
                    int col = wn*64 + n*16 + (l & 15);   // D: col=l&15
                    float v = acc[m][n][rg] + biasAll[nt*256 + col];
                    int off;
                    if (nt < 2)       off = ((bb_*64 + f)*LPAD + t)*256 + col;
                    else if (nt == 2) off = ((bb_*64 + f)*256 + col)*LPAD + t;
                    else if (nt < 5)  off = ((bb_*T_ + t)*64 + f)*256 + col;
                    else              off = ((bb_*T_ + t)*256 + col)*64 + f;
                    dst[off] = (f16)v;
                }
            }
        }
    }
}

// ---------------------------------------------------------------------------
// attn_f: heads (b,f), attention over T (249, padded to 256).
// ---------------------------------------------------------------------------
__global__ __launch_bounds__(256) void attn_f(
    const f16* __restrict__ qf, const f16* __restrict__ kf, const f16* __restrict__ vf,
    const float* __restrict__ alpha, f16* __restrict__ fused)
{
    __shared__ f16 plds[4][16*256];  // wave-private P strips
    const int l = threadIdx.x & 63;
    const int wid = threadIdx.x >> 6;
    const int head = blockIdx.x >> 2;
    const int qb = blockIdx.x & 3;
    const int b = head >> 6, f = head & 63;
    const f16* qh = qf + (size_t)head*LPAD*256;
    const f16* kh = kf + (size_t)head*LPAD*256;
    const f16* vh = vf + (size_t)head*256*LPAD;
    const int qr0 = qb*64 + wid*16;
    f16* pw = &plds[wid][0];

    f16x8 qa[8];
#pragma unroll
    for (int ks = 0; ks < 8; ++ks)
        qa[ks] = *(const f16x8*)(qh + (qr0 + (l & 15))*256 + ks*32 + (l >> 4)*8);

    f32x4 s[16];
#pragma unroll
    for (int nf = 0; nf < 16; ++nf) s[nf] = {0.f, 0.f, 0.f, 0.f};
#pragma unroll
    for (int ks = 0; ks < 8; ++ks)
#pragma unroll
        for (int nf = 0; nf < 16; ++nf) {
            f16x8 bf = *(const f16x8*)(kh + (nf*16 + (l & 15))*256 + ks*32 + (l >> 4)*8);
            s[nf] = mfma16(qa[ks], bf, s[nf]);
        }

    float inv[4];
#pragma unroll
    for (int rg = 0; rg < 4; ++rg) {
        float m = -1e30f;
#pragma unroll
        for (int nf = 0; nf < 16; ++nf)
            if (nf*16 + (l & 15) < T_) m = fmaxf(m, s[nf][rg]);
#pragma unroll
        for (int d = 1; d < 16; d <<= 1) m = fmaxf(m, __shfl_xor(m, d, 64));
        float sum = 0.f;
#pragma unroll
        for (int nf = 0; nf < 16; ++nf) {
            float p = (nf*16 + (l & 15) < T_) ? __expf(s[nf][rg] - m) : 0.f;
            s[nf][rg] = p;   // unnormalized P; 1/sum folded into epilogue
            sum += p;
        }
#pragma unroll
        for (int d = 1; d < 16; d <<= 1) sum += __shfl_xor(sum, d, 64);
        inv[rg] = 1.f / sum;
    }

#pragma unroll
    for (int nf = 0; nf < 16; ++nf)
#pragma unroll
        for (int rg = 0; rg < 4; ++rg) {
            int row = (l >> 4)*4 + rg;
            int col = nf*16 + (l & 15);
            int byte = (row*512 + col*2) ^ ((row & 7) << 4);
            *(f16*)((char*)pw + byte) = (f16)s[nf][rg];
        }

    f32x4 o[16];
#pragma unroll
    for (int nf = 0; nf < 16; ++nf) o[nf] = {0.f, 0.f, 0.f, 0.f};
#pragma unroll
    for (int ks = 0; ks < 8; ++ks) {
        int row = l & 15;
        int cch = ks*4 + (l >> 4);
        int byte = row*512 + ((cch ^ (row & 7)) << 4);
        f16x8 pa = *(const f16x8*)((const char*)pw + byte);
#pragma unroll
        for (int nf = 0; nf < 16; ++nf) {
            f16x8 bf = *(const f16x8*)(vh + (nf*16 + (l & 15))*LPAD + ks*32 + (l >> 4)*8);
            o[nf] = mfma16(pa, bf, o[nf]);
        }
    }

#pragma unroll
    for (int rg = 0; rg < 4; ++rg) {
        int t = qr0 + (l >> 4)*4 + rg;
        if (t < T_) {
#pragma unroll
            for (int nf = 0; nf < 16; ++nf) {
                int c = nf*16 + (l & 15);
                float v = o[nf][rg] * inv[rg] * alpha[((size_t)(b*T_ + t)*64 + f)*256 + c];
                fused[((size_t)(b*TP + t + 1)*FP + (f + 1))*768 + c] = (f16)v;
            }
        }
    }
}

// ---------------------------------------------------------------------------
// attn_t: heads (b,t), attention over F (64, exact).
// ---------------------------------------------------------------------------
__global__ __launch_bounds__(256) void attn_t(
    const f16* __restrict__ qt, const f16* __restrict__ kt, const f16* __restrict__ vt,
    const float* __restrict__ beta, f16* __restrict__ fused)
{
    __shared__ f16 plds[4][16*64];
    const int l = threadIdx.x & 63;
    const int wid = threadIdx.x >> 6;
    const int head = blockIdx.x;        // b*249 + t
    const int b = head / T_, t = head - b*T_;
    const f16* qh = qt + (size_t)head*64*256;
    const f16* kh = kt + (size_t)head*64*256;
    const f16* vh = vt + (size_t)head*256*64;
    const int qr0 = wid*16;
    f16* pw = &plds[wid][0];

    f16x8 qa[8];
#pragma unroll
    for (int ks = 0; ks < 8; ++ks)
        qa[ks] = *(const f16x8*)(qh + (qr0 + (l & 15))*256 + ks*32 + (l >> 4)*8);

    f32x4 s[4];
#pragma unroll
    for (int nf = 0; nf < 4; ++nf) s[nf] = {0.f, 0.f, 0.f, 0.f};
#pragma unroll
    for (int ks = 0; ks < 8; ++ks)
#pragma unroll
        for (int nf = 0; nf < 4; ++nf) {
            f16x8 bf = *(const f16x8*)(kh + (nf*16 + (l & 15))*256 + ks*32 + (l >> 4)*8);
            s[nf] = mfma16(qa[ks], bf, s[nf]);
        }

    float inv[4];
#pragma unroll
    for (int rg = 0; rg < 4; ++rg) {
        float m = -1e30f;
#pragma unroll
        for (int nf = 0; nf < 4; ++nf) m = fmaxf(m, s[nf][rg]);
#pragma unroll
        for (int d = 1; d < 16; d <<= 1) m = fmaxf(m, __shfl_xor(m, d, 64));
        float sum = 0.f;
#pragma unroll
        for (int nf = 0; nf < 4; ++nf) {
            float p = __expf(s[nf][rg] - m);
            s[nf][rg] = p;
            sum += p;
        }
#pragma unroll
        for (int d = 1; d < 16; d <<= 1) sum += __shfl_xor(sum, d, 64);
        inv[rg] = 1.f / sum;
    }

#pragma unroll
    for (int nf = 0; nf < 4; ++nf)
#pragma unroll
        for (int rg = 0; rg < 4; ++rg) {
            int row = (l >> 4)*4 + rg;
            int col = nf*16 + (l & 15);
            int byte = (row*128 + col*2) ^ ((row & 7) << 4);
            *(f16*)((char*)pw + byte) = (f16)s[nf][rg];
        }

    f32x4 o[16];
#pragma unroll
    for (int nf = 0; nf < 16; ++nf) o[nf] = {0.f, 0.f, 0.f, 0.f};
#pragma unroll
    for (int ks = 0; ks < 2; ++ks) {
        int row = l & 15;
        int cch = ks*4 + (l >> 4);
        int byte = row*128 + ((cch ^ (row & 7)) << 4);
        f16x8 pa = *(const f16x8*)((const char*)pw + byte);
#pragma unroll
        for (int nf = 0; nf < 16; ++nf) {
            f16x8 bf = *(const f16x8*)(vh + (nf*16 + (l & 15))*64 + ks*32 + (l >> 4)*8);
            o[nf] = mfma16(pa, bf, o[nf]);
        }
    }

#pragma unroll
    for (int rg = 0; rg < 4; ++rg) {
        int fo = qr0 + (l >> 4)*4 + rg;
#pragma unroll
        for (int nf = 0; nf < 16; ++nf) {
            int c = nf*16 + (l & 15);
            float v = o[nf][rg] * inv[rg] * beta[((size_t)(b*T_ + t)*64 + fo)*256 + c];
            fused[((size_t)(b*TP + t + 1)*FP + (fo + 1))*768 + 256 + c] = (f16)v;
        }
    }
}

// ---------------------------------------------------------------------------
// conv_final: implicit GEMM on fused (padded [B][TP][FP][768]).
//   M tile 64 (grid 498 = one (b,t), all f), N = 64, K = 54 chunks of 128
//   (9 taps x 6). 4 waves, wave tile 16x64, acc 1x4. 2-phase dbuf (r4).
// ---------------------------------------------------------------------------
__global__ __launch_bounds__(256) void conv_final(
    const f16* __restrict__ fused, const f16* __restrict__ wfT,
    const float* __restrict__ biasF, float* __restrict__ out)
{
    __shared__ f16 smem[2][16384];  // per buf: A[0,8192) | B[8192,16384)
    const int l = threadIdx.x & 63;
    const int wid = threadIdx.x >> 6;
    const int mt = blockIdx.x;          // 0..497 = (b,t)
    const int b = mt / T_, t = mt - b*T_;

    int aSrc[4], bSrc[4];
#pragma unroll
    for (int i = 0; i < 4; ++i) {
        int row = i*16 + wid*4 + (l >> 4);
        int ch  = (l & 15) ^ (row & 7);
        aSrc[i] = ((b*TP + t + 1)*FP + (row + 1))*768 + ch*8;   // f = row
        bSrc[i] = row*768 + ch*8;
    }

    int aRowOff, aSwz;
    { int row = wid*16 + (l & 15); aRowOff = row*128; aSwz = row & 7; }
    int bRow[4], bSw[4];
#pragma unroll
    for (int ni = 0; ni < 4; ++ni) {
        int row = ni*16 + (l & 15);
        bRow[ni] = 8192 + row*128; bSw[ni] = row & 7;
    }

    f32x4 acc[4];
#pragma unroll
    for (int ni = 0; ni < 4; ++ni) acc[ni] = {0.f, 0.f, 0.f, 0.f};

#define FSTAGE(KN, NB) do {                                                    \
        int tap_ = (KN) / 6, kc_ = (KN) - ((KN)/6)*6;                          \
        int ash_ = ((tap_/3 - 1)*FP + (tap_%3 - 1))*768 + kc_*128;             \
        const f16* wt_ = wfT + (size_t)tap_*(64*768) + kc_*128;                \
        _Pragma("unroll")                                                      \
        for (int i_ = 0; i_ < 4; ++i_) {                                       \
            gl_lds16(fused + aSrc[i_] + ash_, &smem[NB][(i_*16 + wid*4)*128]); \
            gl_lds16(wt_ + bSrc[i_], &smem[NB][8192 + (i_*16 + wid*4)*128]);   \
        }                                                                      \
    } while (0)

#define FCOMP(NB) do {                                                         \
        _Pragma("unroll")                                                      \
        for (int kk = 0; kk < 4; ++kk) {                                       \
            const int cch = kk*4 + (l >> 4);                                   \
            f16x8 af = *(const f16x8*)(&smem[NB][0] + aRowOff + ((cch ^ aSwz) << 3)); \
            f16x8 bf[4];                                                       \
            _Pragma("unroll")                                                  \
            for (int ni = 0; ni < 4; ++ni)                                     \
                bf[ni] = *(const f16x8*)(&smem[NB][0] + bRow[ni] + ((cch ^ bSw[ni]) << 3)); \
            __builtin_amdgcn_s_setprio(1);                                     \
            _Pragma("unroll")                                                  \
            for (int ni = 0; ni < 4; ++ni)                                     \
                acc[ni] = mfma16(af, bf[ni], acc[ni]);                         \
            __builtin_amdgcn_s_setprio(0);                                     \
        }                                                                      \
    } while (0)

    FSTAGE(0, 0);
    __syncthreads();
    for (int kn = 0; kn < 54; kn += 2) {
        if (kn + 1 < 54) FSTAGE(kn + 1, 1);
        FCOMP(0);
        __syncthreads();
        if (kn + 2 < 54) FSTAGE(kn + 2, 0);
        FCOMP(1);
        __syncthreads();
    }
#undef FSTAGE
#undef FCOMP

#pragma unroll
    for (int rg = 0; rg < 4; ++rg) {
        int f = wid*16 + (l >> 4)*4 + rg;
        int p = mt*64 + f;
#pragma unroll
        for (int ni = 0; ni < 4; ++ni) {
            int oc = ni*16 + (l & 15);
            out[(size_t)p*64 + oc] = acc[ni][rg] + biasF[oc];
        }
    }
}

// ---------------------------------------------------------------------------
extern "C" void kernel_launch(void* const* d_in, const int* in_sizes, int n_in,
                              void* d_out, int out_size, void* d_ws, size_t ws_size,
                              hipStream_t stream) {
    (void)in_sizes; (void)n_in; (void)out_size;
    const float* x    = (const float*)d_in[0];
    const float* wqf  = (const float*)d_in[1];
    const float* bqf  = (const float*)d_in[2];
    const float* wkf  = (const float*)d_in[3];
    const float* bkf  = (const float*)d_in[4];
    const float* wvf  = (const float*)d_in[5];
    const float* bvf  = (const float*)d_in[6];
    const float* wqt  = (const float*)d_in[7];
    const float* bqt  = (const float*)d_in[8];
    const float* wkt  = (const float*)d_in[9];
    const float* bkt  = (const float*)d_in[10];
    const float* wvt  = (const float*)d_in[11];
    const float* bvt  = (const float*)d_in[12];
    const float* wfin = (const float*)d_in[13];
    const float* bfin = (const float*)d_in[14];
    const float* alpha= (const float*)d_in[15];
    const float* beta = (const float*)d_in[16];

    if (ws_size < WS_NEED) return;   // workspace insufficient -> visible failure

    char* ws = (char*)d_ws;
    f16* fused  = (f16*)(ws + OFF_FUSED);
    f16* xpad   = (f16*)(ws + OFF_XPAD);
    f16* qf     = (f16*)(ws + OFF_QF);
    f16* kf     = (f16*)(ws + OFF_KF);
    f16* vf     = (f16*)(ws + OFF_VF);
    f16* qt     = (f16*)(ws + OFF_QT);
    f16* kt     = (f16*)(ws + OFF_KT);
    f16* vt     = (f16*)(ws + OFF_VT);
    f16* wT     = (f16*)(ws + OFF_WT);
    f16* wfT    = (f16*)(ws + OFF_WFT);
    float* bAll = (float*)(ws + OFF_BALL);
    float* bF   = (float*)(ws + OFF_BF);

    // vf must be zero in its pad columns: first call sees arbitrary ws bits
    // (possible NaN) and PV computes 0*V on them.
    hipMemsetAsync(vf, 0, QF_BYTES, stream);

    border_zero<<<dim3(630), dim3(256), 0, stream>>>(xpad, fused);
    prep_w<<<dim3((9*1536*256 + 255)/256), dim3(256), 0, stream>>>(
        wqf, wkf, wvf, wqt, wkt, wvt, wfin,
        bqf, bkf, bvf, bqt, bkt, bvt, bfin, wT, wfT, bAll, bF);
    prep_x<<<dim3(NPIX*32/256), dim3(256), 0, stream>>>(x, xpad, fused);
    conv_qkv<<<dim3(768), dim3(512), 0, stream>>>(xpad, wT, bAll, qf, kf, vf, qt, kt, vt);
    attn_f<<<dim3(512), dim3(256), 0, stream>>>(qf, kf, vf, alpha, fused);
    attn_t<<<dim3(498), dim3(256), 0, stream>>>(qt, kt, vt, beta, fused);
    conv_final<<<dim3(498), dim3(256), 0, stream>>>(fused, wfT, bF, (float*)d_out);
}